// Round 2
// baseline (520.059 us; speedup 1.0000x reference)
//
#include <hip/hip_runtime.h>

#define BB 8
#define CC 96
#define HH 224
#define WW 224

// ---------------------------------------------------------------------------
// Fused haar2d + depthwise 5x5 conv (SAME, zero pad) for one level.
// in:     (B*C, h, w)         raw LL of previous level (or x)
// coeffs: (B*C, 4, h2, w2)    convolved+scaled subband coefficients
// raw_ll: (B*C, h2, w2)       unconvolved LL (input to next level), nullable
// wt:     (4C, 25)            this level's depthwise weights
// wsc:    (4C)                this level's per-channel scale
// ---------------------------------------------------------------------------
__global__ __launch_bounds__(256) void haar_conv_kernel(
    const float* __restrict__ in,
    float* __restrict__ coeffs,
    float* __restrict__ raw_ll,
    const float* __restrict__ wt,
    const float* __restrict__ wsc,
    int h, int w)
{
    const int h2 = h >> 1, w2 = w >> 1;
    const int bc = blockIdx.z;           // b*C + c
    const int c  = bc % CC;
    const int tx = threadIdx.x, ty = threadIdx.y;
    const int tid = ty * 16 + tx;

    __shared__ float s_cur[40][40];   // 32x32 pixel tile + 4-pixel halo
    __shared__ float s_sb[4][20][20]; // 16x16 subband tile + 2 halo
    __shared__ float s_wt[4][25];
    __shared__ float s_sc[4];

    if (tid < 100) {
        int s = tid / 25, k = tid % 25;
        s_wt[s][k] = wt[(c * 4 + s) * 25 + k];
    }
    if (tid < 4) s_sc[tid] = wsc[c * 4 + tid];

    // stage pixel tile, zero-filled outside image (=> subbands outside are 0,
    // matching SAME zero padding of the subband conv)
    const float* inp = in + (size_t)bc * h * w;
    const int gy0 = 32 * blockIdx.y - 4;
    const int gx0 = 32 * blockIdx.x - 4;
    for (int idx = tid; idx < 1600; idx += 256) {
        int r = idx / 40, cl = idx % 40;
        int gr = gy0 + r, gc = gx0 + cl;
        float v = 0.f;
        if (gr >= 0 && gr < h && gc >= 0 && gc < w) v = inp[(size_t)gr * w + gc];
        s_cur[r][cl] = v;
    }
    __syncthreads();

    // haar: 20x20 subband tile
    for (int idx = tid; idx < 400; idx += 256) {
        int sr = idx / 20, sc = idx % 20;
        float a = s_cur[2 * sr][2 * sc];
        float b = s_cur[2 * sr][2 * sc + 1];
        float cv = s_cur[2 * sr + 1][2 * sc];
        float d = s_cur[2 * sr + 1][2 * sc + 1];
        s_sb[0][sr][sc] = 0.5f * (a + b + cv + d);
        s_sb[1][sr][sc] = 0.5f * (a - b + cv - d);
        s_sb[2][sr][sc] = 0.5f * (a + b - cv - d);
        s_sb[3][sr][sc] = 0.5f * (a - b - cv + d);
    }
    __syncthreads();

    const int p = 16 * blockIdx.y + ty;
    const int q = 16 * blockIdx.x + tx;
    if (p < h2 && q < w2) {
        const size_t hw = (size_t)h2 * w2;
        const size_t obase = (size_t)bc * 4 * hw + (size_t)p * w2 + q;
        #pragma unroll
        for (int s = 0; s < 4; ++s) {
            float acc = 0.f;
            #pragma unroll
            for (int ki = 0; ki < 5; ++ki)
                #pragma unroll
                for (int kj = 0; kj < 5; ++kj)
                    acc += s_sb[s][ty + ki][tx + kj] * s_wt[s][ki * 5 + kj];
            coeffs[obase + (size_t)s * hw] = acc * s_sc[s];
        }
        if (raw_ll)
            raw_ll[(size_t)bc * hw + (size_t)p * w2 + q] = s_sb[0][ty + 2][tx + 2];
    }
}

// ---------------------------------------------------------------------------
// Inverse haar with optional LL accumulation.
// coeffs: (B*C,4,h,w), prev: (B*C,h,w) or null, rec: (B*C,2h,2w)
// ---------------------------------------------------------------------------
__global__ __launch_bounds__(256) void ihaar_add_kernel(
    const float* __restrict__ coeffs,
    const float* __restrict__ prev,
    float* __restrict__ rec,
    int h, int w, int total)
{
    int i = blockIdx.x * 256 + threadIdx.x;
    if (i >= total) return;
    int q = i % w;
    int t = i / w;
    int p = t % h;
    int bc = t / h;
    size_t hw = (size_t)h * w;
    size_t base = (size_t)bc * 4 * hw + (size_t)p * w + q;
    float ll = coeffs[base];
    if (prev) ll += prev[(size_t)bc * hw + (size_t)p * w + q];
    float lh = coeffs[base + hw];
    float hl = coeffs[base + 2 * hw];
    float hh = coeffs[base + 3 * hw];
    float a = 0.5f * (ll + lh + hl + hh);
    float b = 0.5f * (ll - lh + hl - hh);
    float cv = 0.5f * (ll + lh - hl - hh);
    float d = 0.5f * (ll - lh - hl + hh);
    float* o = rec + (size_t)bc * 4 * hw + (size_t)(2 * p) * (2 * w) + 2 * q;
    *reinterpret_cast<float2*>(o) = make_float2(a, b);
    *reinterpret_cast<float2*>(o + 2 * w) = make_float2(cv, d);
}

// ---------------------------------------------------------------------------
// Final: base depthwise conv on x (+scale+bias) + level-0 inverse haar
// (with rec1 added into LL), written to out. 224x224, 16x16 tiles.
// ---------------------------------------------------------------------------
__global__ __launch_bounds__(256) void final_kernel(
    const float* __restrict__ x,
    const float* __restrict__ bw,
    const float* __restrict__ bb,
    const float* __restrict__ bs,
    const float* __restrict__ coeffs0, // (B*C,4,112,112)
    const float* __restrict__ rec1,    // (B*C,112,112)
    float* __restrict__ out)
{
    const int bc = blockIdx.z;
    const int c = bc % CC;
    const int tx = threadIdx.x, ty = threadIdx.y;
    const int tid = ty * 16 + tx;
    __shared__ float s_x[20][20];
    __shared__ float s_w[25];
    if (tid < 25) s_w[tid] = bw[c * 25 + tid];
    const float* xp = x + (size_t)bc * HH * WW;
    const int gy0 = 16 * blockIdx.y - 2, gx0 = 16 * blockIdx.x - 2;
    for (int idx = tid; idx < 400; idx += 256) {
        int r = idx / 20, cl = idx % 20;
        int gr = gy0 + r, gc = gx0 + cl;
        float v = 0.f;
        if (gr >= 0 && gr < HH && gc >= 0 && gc < WW) v = xp[gr * WW + gc];
        s_x[r][cl] = v;
    }
    __syncthreads();

    const int Y = 16 * blockIdx.y + ty, X = 16 * blockIdx.x + tx;
    float acc = 0.f;
    #pragma unroll
    for (int ki = 0; ki < 5; ++ki)
        #pragma unroll
        for (int kj = 0; kj < 5; ++kj)
            acc += s_x[ty + ki][tx + kj] * s_w[ki * 5 + kj];
    float base = acc * bs[c] + bb[c];

    const int p = Y >> 1, q = X >> 1;
    const int h2 = HH / 2, w2 = WW / 2;
    const size_t hw = (size_t)h2 * w2;
    const size_t cb = (size_t)bc * 4 * hw + (size_t)p * w2 + q;
    float ll = coeffs0[cb] + rec1[(size_t)bc * hw + (size_t)p * w2 + q];
    float lh = coeffs0[cb + hw];
    float hl = coeffs0[cb + 2 * hw];
    float hh = coeffs0[cb + 3 * hw];
    float sh = (X & 1) ? -1.f : 1.f;
    float sv = (Y & 1) ? -1.f : 1.f;
    float recv = 0.5f * (ll + sh * lh + sv * hl + sh * sv * hh);
    out[(size_t)bc * HH * WW + (size_t)Y * WW + X] = base + recv;
}

extern "C" void kernel_launch(void* const* d_in, const int* in_sizes, int n_in,
                              void* d_out, int out_size, void* d_ws, size_t ws_size,
                              hipStream_t stream) {
    const float* x          = (const float*)d_in[0];
    const float* base_w     = (const float*)d_in[1];
    const float* base_b     = (const float*)d_in[2];
    const float* base_scale = (const float*)d_in[3];
    const float* wconv_w    = (const float*)d_in[4]; // (3, 384, 25)
    const float* wscale     = (const float*)d_in[5]; // (3, 384)
    float* out = (float*)d_out;
    float* ws  = (float*)d_ws;

    const size_t n0 = (size_t)BB * CC * 4 * 112 * 112; // coeffs0
    const size_t n1 = (size_t)BB * CC * 4 * 56 * 56;   // coeffs1
    const size_t n2 = (size_t)BB * CC * 4 * 28 * 28;   // coeffs2
    const size_t m1 = (size_t)BB * CC * 112 * 112;     // cur1 / rec1
    // cur2 / rec2 follows

    float* coeffs0 = ws;
    float* coeffs1 = coeffs0 + n0;
    float* coeffs2 = coeffs1 + n1;
    float* cur1    = coeffs2 + n2;
    float* cur2    = cur1 + m1;

    dim3 blk(16, 16);
    const int z = BB * CC;

    // forward: fused haar + dwconv per level
    haar_conv_kernel<<<dim3(7, 7, z), blk, 0, stream>>>(
        x, coeffs0, cur1, wconv_w + 0 * 384 * 25, wscale + 0 * 384, 224, 224);
    haar_conv_kernel<<<dim3(4, 4, z), blk, 0, stream>>>(
        cur1, coeffs1, cur2, wconv_w + 1 * 384 * 25, wscale + 1 * 384, 112, 112);
    haar_conv_kernel<<<dim3(2, 2, z), blk, 0, stream>>>(
        cur2, coeffs2, nullptr, wconv_w + 2 * 384 * 25, wscale + 2 * 384, 56, 56);

    // reconstruction (reuse cur buffers: forward no longer needs them)
    {
        int total = BB * CC * 28 * 28;
        ihaar_add_kernel<<<(total + 255) / 256, 256, 0, stream>>>(
            coeffs2, nullptr, cur2, 28, 28, total); // rec2 -> cur2 (56x56)
    }
    {
        int total = BB * CC * 56 * 56;
        ihaar_add_kernel<<<(total + 255) / 256, 256, 0, stream>>>(
            coeffs1, cur2, cur1, 56, 56, total);    // rec1 -> cur1 (112x112)
    }

    // base conv + level-0 inverse haar + add
    final_kernel<<<dim3(14, 14, z), blk, 0, stream>>>(
        x, base_w, base_b, base_scale, coeffs0, cur1, out);
}

// Round 3
// 401.574 us; speedup vs baseline: 1.2950x; 1.2950x over previous
//
#include <hip/hip_runtime.h>

#define BB 8
#define CC 96
#define HH 224
#define WW 224

// ---------------------------------------------------------------------------
// Level-0 LL only (for level-1 input): ll[p][q] = 0.5*(2x2 sum of x)
// ---------------------------------------------------------------------------
__global__ __launch_bounds__(256) void haar_ll_kernel(
    const float* __restrict__ x, float* __restrict__ ll)
{
    const int H2 = HH / 2, W2 = WW / 2;   // 112
    const int QG = W2 / 4;                // 28 groups of 4 outputs per row
    int i = blockIdx.x * 256 + threadIdx.x;
    int total = BB * CC * H2 * QG;
    if (i >= total) return;
    int g = i % QG;
    int p = (i / QG) % H2;
    int bc = i / (QG * H2);
    const float* r0 = x + (size_t)bc * HH * WW + (size_t)(2 * p) * WW + 8 * g;
    const float* r1 = r0 + WW;
    float4 a0 = *(const float4*)r0;
    float4 a1 = *(const float4*)(r0 + 4);
    float4 b0 = *(const float4*)r1;
    float4 b1 = *(const float4*)(r1 + 4);
    float4 o;
    o.x = 0.5f * (a0.x + a0.y + b0.x + b0.y);
    o.y = 0.5f * (a0.z + a0.w + b0.z + b0.w);
    o.z = 0.5f * (a1.x + a1.y + b1.x + b1.y);
    o.w = 0.5f * (a1.z + a1.w + b1.z + b1.w);
    *(float4*)(ll + (size_t)bc * H2 * W2 + (size_t)p * W2 + 4 * g) = o;
}

// ---------------------------------------------------------------------------
// Fused haar2d + depthwise 5x5 conv (SAME, zero pad) — levels 1,2 only now.
// ---------------------------------------------------------------------------
__global__ __launch_bounds__(256) void haar_conv_kernel(
    const float* __restrict__ in,
    float* __restrict__ coeffs,
    float* __restrict__ raw_ll,
    const float* __restrict__ wt,
    const float* __restrict__ wsc,
    int h, int w)
{
    const int h2 = h >> 1, w2 = w >> 1;
    const int bc = blockIdx.z;
    const int c  = bc % CC;
    const int tx = threadIdx.x, ty = threadIdx.y;
    const int tid = ty * 16 + tx;

    __shared__ float s_cur[40][40];
    __shared__ float s_sb[4][20][24];   // padded stride 24: uniform 2-way
    __shared__ float s_wt[4][25];
    __shared__ float s_sc[4];

    if (tid < 100) {
        int s = tid / 25, k = tid % 25;
        s_wt[s][k] = wt[(c * 4 + s) * 25 + k];
    }
    if (tid < 4) s_sc[tid] = wsc[c * 4 + tid];

    const float* inp = in + (size_t)bc * h * w;
    const int gy0 = 32 * blockIdx.y - 4;
    const int gx0 = 32 * blockIdx.x - 4;
    for (int idx = tid; idx < 1600; idx += 256) {
        int r = idx / 40, cl = idx % 40;
        int gr = gy0 + r, gc = gx0 + cl;
        float v = 0.f;
        if (gr >= 0 && gr < h && gc >= 0 && gc < w) v = inp[(size_t)gr * w + gc];
        s_cur[r][cl] = v;
    }
    __syncthreads();

    for (int idx = tid; idx < 400; idx += 256) {
        int sr = idx / 20, sc = idx % 20;
        float a = s_cur[2 * sr][2 * sc];
        float b = s_cur[2 * sr][2 * sc + 1];
        float cv = s_cur[2 * sr + 1][2 * sc];
        float d = s_cur[2 * sr + 1][2 * sc + 1];
        s_sb[0][sr][sc] = 0.5f * (a + b + cv + d);
        s_sb[1][sr][sc] = 0.5f * (a - b + cv - d);
        s_sb[2][sr][sc] = 0.5f * (a + b - cv - d);
        s_sb[3][sr][sc] = 0.5f * (a - b - cv + d);
    }
    __syncthreads();

    const int p = 16 * blockIdx.y + ty;
    const int q = 16 * blockIdx.x + tx;
    if (p < h2 && q < w2) {
        const size_t hw = (size_t)h2 * w2;
        const size_t obase = (size_t)bc * 4 * hw + (size_t)p * w2 + q;
        #pragma unroll
        for (int s = 0; s < 4; ++s) {
            float acc = 0.f;
            #pragma unroll
            for (int ki = 0; ki < 5; ++ki)
                #pragma unroll
                for (int kj = 0; kj < 5; ++kj)
                    acc += s_sb[s][ty + ki][tx + kj] * s_wt[s][ki * 5 + kj];
            coeffs[obase + (size_t)s * hw] = acc * s_sc[s];
        }
        if (raw_ll)
            raw_ll[(size_t)bc * hw + (size_t)p * w2 + q] = s_sb[0][ty + 2][tx + 2];
    }
}

// ---------------------------------------------------------------------------
// Inverse haar with optional LL accumulation.
// ---------------------------------------------------------------------------
__global__ __launch_bounds__(256) void ihaar_add_kernel(
    const float* __restrict__ coeffs,
    const float* __restrict__ prev,
    float* __restrict__ rec,
    int h, int w, int total)
{
    int i = blockIdx.x * 256 + threadIdx.x;
    if (i >= total) return;
    int q = i % w;
    int t = i / w;
    int p = t % h;
    int bc = t / h;
    size_t hw = (size_t)h * w;
    size_t base = (size_t)bc * 4 * hw + (size_t)p * w + q;
    float ll = coeffs[base];
    if (prev) ll += prev[(size_t)bc * hw + (size_t)p * w + q];
    float lh = coeffs[base + hw];
    float hl = coeffs[base + 2 * hw];
    float hh = coeffs[base + 3 * hw];
    float a = 0.5f * (ll + lh + hl + hh);
    float b = 0.5f * (ll - lh + hl - hh);
    float cv = 0.5f * (ll + lh - hl - hh);
    float d = 0.5f * (ll - lh - hl + hh);
    float* o = rec + (size_t)bc * 4 * hw + (size_t)(2 * p) * (2 * w) + 2 * q;
    *reinterpret_cast<float2*>(o) = make_float2(a, b);
    *reinterpret_cast<float2*>(o + 2 * w) = make_float2(cv, d);
}

// ---------------------------------------------------------------------------
// Fully fused final: base conv(x) + level-0 haar + dwconv + (+rec1) + ihaar.
// 32x32 output tile per block; x staged column-parity-split to kill bank
// conflicts on both haar (stride-2) and base-conv reads.
// ---------------------------------------------------------------------------
__global__ __launch_bounds__(256) void final_fused_kernel(
    const float* __restrict__ x,
    const float* __restrict__ bw,    // (C,25)
    const float* __restrict__ bb,    // (C)
    const float* __restrict__ bs,    // (C)
    const float* __restrict__ wt0,   // (4C,25) level-0
    const float* __restrict__ wsc0,  // (4C)
    const float* __restrict__ rec1,  // (B*C,112,112)
    float* __restrict__ out)
{
    const int bc = blockIdx.z, c = bc % CC;
    const int tx = threadIdx.x, ty = threadIdx.y;
    const int tid = ty * 16 + tx;

    __shared__ float s_x[2][40][20];   // [col parity][row][col/2], 40x40 tile
    __shared__ float s_sb[4][20][24];  // subbands, padded
    __shared__ float s_wt[4][25];
    __shared__ float s_bw[25];
    __shared__ float s_sc[4];

    if (tid < 100) { int s = tid / 25, k = tid % 25; s_wt[s][k] = wt0[(c * 4 + s) * 25 + k]; }
    else if (tid >= 128 && tid < 153) s_bw[tid - 128] = bw[c * 25 + tid - 128];
    if (tid < 4) s_sc[tid] = wsc0[c * 4 + tid];

    const float* xp = x + (size_t)bc * HH * WW;
    const int gy0 = 32 * blockIdx.y - 4;
    const int gx0 = 32 * blockIdx.x - 4;
    for (int idx = tid; idx < 1600; idx += 256) {
        int r = idx / 40, cl = idx % 40;
        int gr = gy0 + r, gc = gx0 + cl;
        float v = 0.f;
        if (gr >= 0 && gr < HH && gc >= 0 && gc < WW) v = xp[(size_t)gr * WW + gc];
        s_x[cl & 1][r][cl >> 1] = v;
    }
    __syncthreads();

    for (int idx = tid; idx < 400; idx += 256) {
        int sr = idx / 20, sc = idx % 20;
        float a  = s_x[0][2 * sr][sc];
        float b  = s_x[1][2 * sr][sc];
        float cv = s_x[0][2 * sr + 1][sc];
        float d  = s_x[1][2 * sr + 1][sc];
        s_sb[0][sr][sc] = 0.5f * (a + b + cv + d);
        s_sb[1][sr][sc] = 0.5f * (a - b + cv - d);
        s_sb[2][sr][sc] = 0.5f * (a + b - cv - d);
        s_sb[3][sr][sc] = 0.5f * (a - b - cv + d);
    }
    __syncthreads();

    const int p = 16 * blockIdx.y + ty;   // 0..111 exact (7*16=112)
    const int q = 16 * blockIdx.x + tx;

    // level-0 subband convs
    float sb[4];
    #pragma unroll
    for (int s = 0; s < 4; ++s) {
        float acc = 0.f;
        #pragma unroll
        for (int ki = 0; ki < 5; ++ki)
            #pragma unroll
            for (int kj = 0; kj < 5; ++kj)
                acc += s_sb[s][ty + ki][tx + kj] * s_wt[s][ki * 5 + kj];
        sb[s] = acc * s_sc[s];
    }
    float ll = sb[0] + rec1[(size_t)bc * 112 * 112 + (size_t)p * 112 + q];
    float av = 0.5f * (ll + sb[1] + sb[2] + sb[3]);
    float bv = 0.5f * (ll - sb[1] + sb[2] - sb[3]);
    float cvv = 0.5f * (ll + sb[1] - sb[2] - sb[3]);
    float dv = 0.5f * (ll - sb[1] - sb[2] + sb[3]);

    // base 5x5 conv for this thread's 2x2 output pixels
    float bsc = bs[c], bbv = bb[c];
    float basev[2][2];
    #pragma unroll
    for (int dy = 0; dy < 2; ++dy)
        #pragma unroll
        for (int dx = 0; dx < 2; ++dx) {
            float acc = 0.f;
            #pragma unroll
            for (int ki = 0; ki < 5; ++ki)
                #pragma unroll
                for (int kj = 0; kj < 5; ++kj) {
                    int rr = 2 * ty + dy + ki + 2;       // row in 40x40 tile
                    int colt = 2 * tx + dx + kj + 2;     // col in 40x40 tile
                    acc += s_x[colt & 1][rr][colt >> 1] * s_bw[ki * 5 + kj];
                }
            basev[dy][dx] = acc * bsc + bbv;
        }

    float* orow = out + (size_t)bc * HH * WW + (size_t)(2 * p) * WW + 2 * q;
    *reinterpret_cast<float2*>(orow)      = make_float2(basev[0][0] + av,  basev[0][1] + bv);
    *reinterpret_cast<float2*>(orow + WW) = make_float2(basev[1][0] + cvv, basev[1][1] + dv);
}

extern "C" void kernel_launch(void* const* d_in, const int* in_sizes, int n_in,
                              void* d_out, int out_size, void* d_ws, size_t ws_size,
                              hipStream_t stream) {
    const float* x          = (const float*)d_in[0];
    const float* base_w     = (const float*)d_in[1];
    const float* base_b     = (const float*)d_in[2];
    const float* base_scale = (const float*)d_in[3];
    const float* wconv_w    = (const float*)d_in[4]; // (3, 384, 25)
    const float* wscale     = (const float*)d_in[5]; // (3, 384)
    float* out = (float*)d_out;
    float* ws  = (float*)d_ws;

    const size_t n1 = (size_t)BB * CC * 4 * 56 * 56;   // coeffs1
    const size_t n2 = (size_t)BB * CC * 4 * 28 * 28;   // coeffs2
    const size_t m1 = (size_t)BB * CC * 112 * 112;     // cur1 / rec1
    // cur2 / rec2 follows

    float* coeffs1 = ws;
    float* coeffs2 = coeffs1 + n1;
    float* cur1    = coeffs2 + n2;
    float* cur2    = cur1 + m1;

    dim3 blk(16, 16);
    const int z = BB * CC;

    // level-0 LL (input to level 1)
    {
        int total = BB * CC * 112 * 28;
        haar_ll_kernel<<<(total + 255) / 256, 256, 0, stream>>>(x, cur1);
    }
    // levels 1,2: fused haar + dwconv
    haar_conv_kernel<<<dim3(4, 4, z), blk, 0, stream>>>(
        cur1, coeffs1, cur2, wconv_w + 1 * 384 * 25, wscale + 1 * 384, 112, 112);
    haar_conv_kernel<<<dim3(2, 2, z), blk, 0, stream>>>(
        cur2, coeffs2, nullptr, wconv_w + 2 * 384 * 25, wscale + 2 * 384, 56, 56);

    // reconstruction of levels 2,1 (reuse cur buffers)
    {
        int total = BB * CC * 28 * 28;
        ihaar_add_kernel<<<(total + 255) / 256, 256, 0, stream>>>(
            coeffs2, nullptr, cur2, 28, 28, total);   // rec2 (56x56) -> cur2
    }
    {
        int total = BB * CC * 56 * 56;
        ihaar_add_kernel<<<(total + 255) / 256, 256, 0, stream>>>(
            coeffs1, cur2, cur1, 56, 56, total);      // rec1 (112x112) -> cur1
    }

    // fused: base conv + level-0 haar+conv (+rec1) + inverse haar
    final_fused_kernel<<<dim3(7, 7, z), blk, 0, stream>>>(
        x, base_w, base_b, base_scale,
        wconv_w + 0 * 384 * 25, wscale + 0 * 384, cur1, out);
}

// Round 4
// 311.121 us; speedup vs baseline: 1.6716x; 1.2907x over previous
//
#include <hip/hip_runtime.h>

#define BB 8
#define CC 96
#define HH 224
#define WW 224

// ---------------------------------------------------------------------------
// Level-0 LL only (for level-1 input): ll[p][q] = 0.5*(2x2 sum of x)
// ---------------------------------------------------------------------------
__global__ __launch_bounds__(256) void haar_ll_kernel(
    const float* __restrict__ x, float* __restrict__ ll)
{
    const int H2 = HH / 2, W2 = WW / 2;   // 112
    const int QG = W2 / 4;                // 28 groups of 4 outputs per row
    int i = blockIdx.x * 256 + threadIdx.x;
    int total = BB * CC * H2 * QG;
    if (i >= total) return;
    int g = i % QG;
    int p = (i / QG) % H2;
    int bc = i / (QG * H2);
    const float* r0 = x + (size_t)bc * HH * WW + (size_t)(2 * p) * WW + 8 * g;
    const float* r1 = r0 + WW;
    float4 a0 = *(const float4*)r0;
    float4 a1 = *(const float4*)(r0 + 4);
    float4 b0 = *(const float4*)r1;
    float4 b1 = *(const float4*)(r1 + 4);
    float4 o;
    o.x = 0.5f * (a0.x + a0.y + b0.x + b0.y);
    o.y = 0.5f * (a0.z + a0.w + b0.z + b0.w);
    o.z = 0.5f * (a1.x + a1.y + b1.x + b1.y);
    o.w = 0.5f * (a1.z + a1.w + b1.z + b1.w);
    *(float4*)(ll + (size_t)bc * H2 * W2 + (size_t)p * W2 + 4 * g) = o;
}

// ---------------------------------------------------------------------------
// haar + dwconv, column-sliding version (levels 1,2).
// grid (h2/28, h2/28, B*C), 256 threads.
// Phases: stage 64x64 input tile -> haar butterfly (32x32 subband halo tile)
// -> per-thread 14-tall column conv (6.4 LDS reads/output instead of 25).
// ---------------------------------------------------------------------------
__global__ __launch_bounds__(256) void haar_conv_v2(
    const float* __restrict__ in,
    float* __restrict__ coeffs,
    float* __restrict__ raw_ll,
    const float* __restrict__ wt,
    const float* __restrict__ wsc,
    int h)
{
    const int h2 = h >> 1;
    const int bc = blockIdx.z, c = bc % CC;
    const int t = threadIdx.x;

    __shared__ float s_x[64 * 65];
    __shared__ float s_sb[4][32 * 33];
    __shared__ float s_wt[4][25];
    __shared__ float s_sc[4];

    if (t < 100) { int s = t / 25, k = t % 25; s_wt[s][k] = wt[(c * 4 + s) * 25 + k]; }
    if (t >= 128 && t < 132) s_sc[t - 128] = wsc[c * 4 + (t - 128)];

    const float* inp = in + (size_t)bc * h * h;
    const int gy0 = 56 * blockIdx.y - 4, gx0 = 56 * blockIdx.x - 4;
    for (int idx = t; idx < 4096; idx += 256) {
        int r = idx >> 6, cl = idx & 63;
        int gr = gy0 + r, gc = gx0 + cl;
        float v = 0.f;
        if (gr >= 0 && gr < h && gc >= 0 && gc < h) v = inp[(size_t)gr * h + gc];
        s_x[r * 65 + cl] = v;
    }
    __syncthreads();

    for (int idx = t; idx < 1024; idx += 256) {
        int sr = idx >> 5, sc2 = idx & 31;
        const float* p0 = &s_x[(2 * sr) * 65 + 2 * sc2];
        float a = p0[0], b = p0[1], cv = p0[65], d = p0[66];
        s_sb[0][sr * 33 + sc2] = 0.5f * (a + b + cv + d);
        s_sb[1][sr * 33 + sc2] = 0.5f * (a - b + cv - d);
        s_sb[2][sr * 33 + sc2] = 0.5f * (a + b - cv - d);
        s_sb[3][sr * 33 + sc2] = 0.5f * (a - b - cv + d);
    }
    __syncthreads();

    const int s = t >> 6, u = t & 63;
    if (u < 56) {
        const int q = u % 28, rb = u / 28;
        float w[25];
        #pragma unroll
        for (int k = 0; k < 25; ++k) w[k] = s_wt[s][k];
        const float scale = s_sc[s];
        float acc[14];
        #pragma unroll
        for (int r = 0; r < 14; ++r) acc[r] = 0.f;

        const int p0g = 28 * blockIdx.y + rb * 14;
        const int qg  = 28 * blockIdx.x + q;

        #pragma unroll
        for (int ri = 0; ri < 18; ++ri) {
            const float* rp = &s_sb[s][(rb * 14 + ri) * 33 + q];
            float v0 = rp[0], v1 = rp[1], v2 = rp[2], v3 = rp[3], v4 = rp[4];
            if (s == 0 && raw_ll && ri >= 2 && ri < 16)
                raw_ll[((size_t)bc * h2 + (p0g + ri - 2)) * h2 + qg] = v2;
            #pragma unroll
            for (int ki = 0; ki < 5; ++ki) {
                int r = ri - ki;
                if (r >= 0 && r < 14)
                    acc[r] += v0 * w[ki * 5] + v1 * w[ki * 5 + 1] + v2 * w[ki * 5 + 2]
                            + v3 * w[ki * 5 + 3] + v4 * w[ki * 5 + 4];
            }
        }
        const size_t ob = ((size_t)(bc * 4 + s) * h2 + p0g) * h2 + qg;
        #pragma unroll
        for (int r = 0; r < 14; ++r)
            coeffs[ob + (size_t)r * h2] = acc[r] * scale;
    }
}

// ---------------------------------------------------------------------------
// Inverse haar with optional LL accumulation (unchanged).
// ---------------------------------------------------------------------------
__global__ __launch_bounds__(256) void ihaar_add_kernel(
    const float* __restrict__ coeffs,
    const float* __restrict__ prev,
    float* __restrict__ rec,
    int h, int w, int total)
{
    int i = blockIdx.x * 256 + threadIdx.x;
    if (i >= total) return;
    int q = i % w;
    int t = i / w;
    int p = t % h;
    int bc = t / h;
    size_t hw = (size_t)h * w;
    size_t base = (size_t)bc * 4 * hw + (size_t)p * w + q;
    float ll = coeffs[base];
    if (prev) ll += prev[(size_t)bc * hw + (size_t)p * w + q];
    float lh = coeffs[base + hw];
    float hl = coeffs[base + 2 * hw];
    float hh = coeffs[base + 3 * hw];
    float a = 0.5f * (ll + lh + hl + hh);
    float b = 0.5f * (ll - lh + hl - hh);
    float cv = 0.5f * (ll + lh - hl - hh);
    float d = 0.5f * (ll - lh - hl + hh);
    float* o = rec + (size_t)bc * 4 * hw + (size_t)(2 * p) * (2 * w) + 2 * q;
    *reinterpret_cast<float2*>(o) = make_float2(a, b);
    *reinterpret_cast<float2*>(o + 2 * w) = make_float2(cv, d);
}

// ---------------------------------------------------------------------------
// Final fused, column-sliding: base conv(x) + L0 haar + dwconv + (+rec1)
// + inverse haar. 56x56 output tile, 64x64 x-tile, 256 threads.
// ---------------------------------------------------------------------------
__global__ __launch_bounds__(256) void final_fused_v2(
    const float* __restrict__ x,
    const float* __restrict__ bw,
    const float* __restrict__ bb,
    const float* __restrict__ bs,
    const float* __restrict__ wt0,
    const float* __restrict__ wsc0,
    const float* __restrict__ rec1,
    float* __restrict__ out)
{
    const int bc = blockIdx.z, c = bc % CC;
    const int t = threadIdx.x;

    __shared__ float s_x[64 * 65];
    __shared__ float s_sb[4][32 * 33];
    __shared__ float s_cv[4][28 * 29];
    __shared__ float s_wt[4][25];
    __shared__ float s_bw[25];
    __shared__ float s_sc[4];

    if (t < 100) { int s = t / 25, k = t % 25; s_wt[s][k] = wt0[(c * 4 + s) * 25 + k]; }
    if (t >= 128 && t < 153) s_bw[t - 128] = bw[c * 25 + (t - 128)];
    if (t >= 192 && t < 196) s_sc[t - 192] = wsc0[c * 4 + (t - 192)];

    const float* xp = x + (size_t)bc * HH * WW;
    const int gy0 = 56 * blockIdx.y - 4, gx0 = 56 * blockIdx.x - 4;
    for (int idx = t; idx < 4096; idx += 256) {
        int r = idx >> 6, cl = idx & 63;
        int gr = gy0 + r, gc = gx0 + cl;
        float v = 0.f;
        if (gr >= 0 && gr < HH && gc >= 0 && gc < WW) v = xp[(size_t)gr * WW + gc];
        s_x[r * 65 + cl] = v;
    }
    __syncthreads();

    for (int idx = t; idx < 1024; idx += 256) {
        int sr = idx >> 5, sc2 = idx & 31;
        const float* p0 = &s_x[(2 * sr) * 65 + 2 * sc2];
        float a = p0[0], b = p0[1], cv = p0[65], d = p0[66];
        s_sb[0][sr * 33 + sc2] = 0.5f * (a + b + cv + d);
        s_sb[1][sr * 33 + sc2] = 0.5f * (a - b + cv - d);
        s_sb[2][sr * 33 + sc2] = 0.5f * (a + b - cv - d);
        s_sb[3][sr * 33 + sc2] = 0.5f * (a - b - cv + d);
    }
    __syncthreads();

    // level-0 subband convs -> s_cv
    {
        const int s = t >> 6, u = t & 63;
        if (u < 56) {
            const int q = u % 28, rb = u / 28;
            float w[25];
            #pragma unroll
            for (int k = 0; k < 25; ++k) w[k] = s_wt[s][k];
            const float scale = s_sc[s];
            float acc[14];
            #pragma unroll
            for (int r = 0; r < 14; ++r) acc[r] = 0.f;
            #pragma unroll
            for (int ri = 0; ri < 18; ++ri) {
                const float* rp = &s_sb[s][(rb * 14 + ri) * 33 + q];
                float v0 = rp[0], v1 = rp[1], v2 = rp[2], v3 = rp[3], v4 = rp[4];
                #pragma unroll
                for (int ki = 0; ki < 5; ++ki) {
                    int r = ri - ki;
                    if (r >= 0 && r < 14)
                        acc[r] += v0 * w[ki * 5] + v1 * w[ki * 5 + 1] + v2 * w[ki * 5 + 2]
                                + v3 * w[ki * 5 + 3] + v4 * w[ki * 5 + 4];
                }
            }
            #pragma unroll
            for (int r = 0; r < 14; ++r)
                s_cv[s][(rb * 14 + r) * 29 + q] = acc[r] * scale;
        }
    }
    __syncthreads();

    // base conv + inverse haar + store
    if (t < 224) {
        const int q = t % 56, rb = t / 56;
        float w[25];
        #pragma unroll
        for (int k = 0; k < 25; ++k) w[k] = s_bw[k];
        float bacc[14];
        #pragma unroll
        for (int r = 0; r < 14; ++r) bacc[r] = 0.f;
        #pragma unroll
        for (int ri = 0; ri < 18; ++ri) {
            const float* rp = &s_x[(rb * 14 + ri + 2) * 65 + q + 2];
            float v0 = rp[0], v1 = rp[1], v2 = rp[2], v3 = rp[3], v4 = rp[4];
            #pragma unroll
            for (int ki = 0; ki < 5; ++ki) {
                int r = ri - ki;
                if (r >= 0 && r < 14)
                    bacc[r] += v0 * w[ki * 5] + v1 * w[ki * 5 + 1] + v2 * w[ki * 5 + 2]
                             + v3 * w[ki * 5 + 3] + v4 * w[ki * 5 + 4];
            }
        }
        const float bsc = bs[c], bbv = bb[c];
        const int qs = q >> 1;
        const float sx = (q & 1) ? -1.f : 1.f;
        const int pg0 = 28 * blockIdx.y;
        const int qg = 28 * blockIdx.x + qs;
        const float* recp = rec1 + ((size_t)bc * 112 + pg0) * 112 + qg;
        float* op = out + ((size_t)bc * HH + 56 * blockIdx.y + rb * 14) * WW
                        + 56 * blockIdx.x + q;
        #pragma unroll
        for (int j = 0; j < 7; ++j) {
            const int p = rb * 7 + j;
            float ll = s_cv[0][p * 29 + qs] + recp[(size_t)p * 112];
            float lh = s_cv[1][p * 29 + qs];
            float hl = s_cv[2][p * 29 + qs];
            float hh = s_cv[3][p * 29 + qs];
            float e0 = ll + sx * lh;
            float e1 = hl + sx * hh;
            float top = 0.5f * (e0 + e1);
            float bot = 0.5f * (e0 - e1);
            op[(size_t)(2 * j) * WW]     = bacc[2 * j] * bsc + bbv + top;
            op[(size_t)(2 * j + 1) * WW] = bacc[2 * j + 1] * bsc + bbv + bot;
        }
    }
}

extern "C" void kernel_launch(void* const* d_in, const int* in_sizes, int n_in,
                              void* d_out, int out_size, void* d_ws, size_t ws_size,
                              hipStream_t stream) {
    const float* x          = (const float*)d_in[0];
    const float* base_w     = (const float*)d_in[1];
    const float* base_b     = (const float*)d_in[2];
    const float* base_scale = (const float*)d_in[3];
    const float* wconv_w    = (const float*)d_in[4]; // (3, 384, 25)
    const float* wscale     = (const float*)d_in[5]; // (3, 384)
    float* out = (float*)d_out;
    float* ws  = (float*)d_ws;

    const size_t n1 = (size_t)BB * CC * 4 * 56 * 56;   // coeffs1
    const size_t n2 = (size_t)BB * CC * 4 * 28 * 28;   // coeffs2
    const size_t m1 = (size_t)BB * CC * 112 * 112;     // cur1 / rec1

    float* coeffs1 = ws;
    float* coeffs2 = coeffs1 + n1;
    float* cur1    = coeffs2 + n2;
    float* cur2    = cur1 + m1;

    const int z = BB * CC;

    // level-0 LL (input to level 1)
    {
        int total = BB * CC * 112 * 28;
        haar_ll_kernel<<<(total + 255) / 256, 256, 0, stream>>>(x, cur1);
    }
    // levels 1,2: fused haar + dwconv (column-sliding)
    haar_conv_v2<<<dim3(2, 2, z), 256, 0, stream>>>(
        cur1, coeffs1, cur2, wconv_w + 1 * 384 * 25, wscale + 1 * 384, 112);
    haar_conv_v2<<<dim3(1, 1, z), 256, 0, stream>>>(
        cur2, coeffs2, nullptr, wconv_w + 2 * 384 * 25, wscale + 2 * 384, 56);

    // reconstruction of levels 2,1 (reuse cur buffers)
    {
        int total = BB * CC * 28 * 28;
        ihaar_add_kernel<<<(total + 255) / 256, 256, 0, stream>>>(
            coeffs2, nullptr, cur2, 28, 28, total);   // rec2 (56x56) -> cur2
    }
    {
        int total = BB * CC * 56 * 56;
        ihaar_add_kernel<<<(total + 255) / 256, 256, 0, stream>>>(
            coeffs1, cur2, cur1, 56, 56, total);      // rec1 (112x112) -> cur1
    }

    // fused: base conv + level-0 haar+conv (+rec1) + inverse haar
    final_fused_v2<<<dim3(4, 4, z), 256, 0, stream>>>(
        x, base_w, base_b, base_scale,
        wconv_w + 0 * 384 * 25, wscale + 0 * 384, cur1, out);
}

// Round 5
// 221.284 us; speedup vs baseline: 2.3502x; 1.4060x over previous
//
#include <hip/hip_runtime.h>

#define BB 8
#define CC 96
#define HH 224
#define WW 224

// ---------------------------------------------------------------------------
// Level-0 LL only (for level-1 input): ll[p][q] = 0.5*(2x2 sum of x)
// ---------------------------------------------------------------------------
__global__ __launch_bounds__(256) void haar_ll_kernel(
    const float* __restrict__ x, float* __restrict__ ll)
{
    const int H2 = HH / 2, W2 = WW / 2;   // 112
    const int QG = W2 / 4;                // 28 groups of 4 outputs per row
    int i = blockIdx.x * 256 + threadIdx.x;
    int total = BB * CC * H2 * QG;
    if (i >= total) return;
    int g = i % QG;
    int p = (i / QG) % H2;
    int bc = i / (QG * H2);
    const float* r0 = x + (size_t)bc * HH * WW + (size_t)(2 * p) * WW + 8 * g;
    const float* r1 = r0 + WW;
    float4 a0 = *(const float4*)r0;
    float4 a1 = *(const float4*)(r0 + 4);
    float4 b0 = *(const float4*)r1;
    float4 b1 = *(const float4*)(r1 + 4);
    float4 o;
    o.x = 0.5f * (a0.x + a0.y + b0.x + b0.y);
    o.y = 0.5f * (a0.z + a0.w + b0.z + b0.w);
    o.z = 0.5f * (a1.x + a1.y + b1.x + b1.y);
    o.w = 0.5f * (a1.z + a1.w + b1.z + b1.w);
    *(float4*)(ll + (size_t)bc * H2 * W2 + (size_t)p * W2 + 4 * g) = o;
}

// ---------------------------------------------------------------------------
// haar + dwconv, column-sliding version (levels 1,2). Unchanged from v2.
// ---------------------------------------------------------------------------
__global__ __launch_bounds__(256) void haar_conv_v2(
    const float* __restrict__ in,
    float* __restrict__ coeffs,
    float* __restrict__ raw_ll,
    const float* __restrict__ wt,
    const float* __restrict__ wsc,
    int h)
{
    const int h2 = h >> 1;
    const int bc = blockIdx.z, c = bc % CC;
    const int t = threadIdx.x;

    __shared__ float s_x[64 * 65];
    __shared__ float s_sb[4][32 * 33];
    __shared__ float s_wt[4][25];
    __shared__ float s_sc[4];

    if (t < 100) { int s = t / 25, k = t % 25; s_wt[s][k] = wt[(c * 4 + s) * 25 + k]; }
    if (t >= 128 && t < 132) s_sc[t - 128] = wsc[c * 4 + (t - 128)];

    const float* inp = in + (size_t)bc * h * h;
    const int gy0 = 56 * blockIdx.y - 4, gx0 = 56 * blockIdx.x - 4;
    for (int idx = t; idx < 4096; idx += 256) {
        int r = idx >> 6, cl = idx & 63;
        int gr = gy0 + r, gc = gx0 + cl;
        float v = 0.f;
        if (gr >= 0 && gr < h && gc >= 0 && gc < h) v = inp[(size_t)gr * h + gc];
        s_x[r * 65 + cl] = v;
    }
    __syncthreads();

    for (int idx = t; idx < 1024; idx += 256) {
        int sr = idx >> 5, sc2 = idx & 31;
        const float* p0 = &s_x[(2 * sr) * 65 + 2 * sc2];
        float a = p0[0], b = p0[1], cv = p0[65], d = p0[66];
        s_sb[0][sr * 33 + sc2] = 0.5f * (a + b + cv + d);
        s_sb[1][sr * 33 + sc2] = 0.5f * (a - b + cv - d);
        s_sb[2][sr * 33 + sc2] = 0.5f * (a + b - cv - d);
        s_sb[3][sr * 33 + sc2] = 0.5f * (a - b - cv + d);
    }
    __syncthreads();

    const int s = t >> 6, u = t & 63;
    if (u < 56) {
        const int q = u % 28, rb = u / 28;
        float w[25];
        #pragma unroll
        for (int k = 0; k < 25; ++k) w[k] = s_wt[s][k];
        const float scale = s_sc[s];
        float acc[14];
        #pragma unroll
        for (int r = 0; r < 14; ++r) acc[r] = 0.f;

        const int p0g = 28 * blockIdx.y + rb * 14;
        const int qg  = 28 * blockIdx.x + q;

        #pragma unroll
        for (int ri = 0; ri < 18; ++ri) {
            const float* rp = &s_sb[s][(rb * 14 + ri) * 33 + q];
            float v0 = rp[0], v1 = rp[1], v2 = rp[2], v3 = rp[3], v4 = rp[4];
            if (s == 0 && raw_ll && ri >= 2 && ri < 16)
                raw_ll[((size_t)bc * h2 + (p0g + ri - 2)) * h2 + qg] = v2;
            #pragma unroll
            for (int ki = 0; ki < 5; ++ki) {
                int r = ri - ki;
                if (r >= 0 && r < 14)
                    acc[r] += v0 * w[ki * 5] + v1 * w[ki * 5 + 1] + v2 * w[ki * 5 + 2]
                            + v3 * w[ki * 5 + 3] + v4 * w[ki * 5 + 4];
            }
        }
        const size_t ob = ((size_t)(bc * 4 + s) * h2 + p0g) * h2 + qg;
        #pragma unroll
        for (int r = 0; r < 14; ++r)
            coeffs[ob + (size_t)r * h2] = acc[r] * scale;
    }
}

// ---------------------------------------------------------------------------
// Inverse haar with optional LL accumulation (unchanged).
// ---------------------------------------------------------------------------
__global__ __launch_bounds__(256) void ihaar_add_kernel(
    const float* __restrict__ coeffs,
    const float* __restrict__ prev,
    float* __restrict__ rec,
    int h, int w, int total)
{
    int i = blockIdx.x * 256 + threadIdx.x;
    if (i >= total) return;
    int q = i % w;
    int t = i / w;
    int p = t % h;
    int bc = t / h;
    size_t hw = (size_t)h * w;
    size_t base = (size_t)bc * 4 * hw + (size_t)p * w + q;
    float ll = coeffs[base];
    if (prev) ll += prev[(size_t)bc * hw + (size_t)p * w + q];
    float lh = coeffs[base + hw];
    float hl = coeffs[base + 2 * hw];
    float hh = coeffs[base + 3 * hw];
    float a = 0.5f * (ll + lh + hl + hh);
    float b = 0.5f * (ll - lh + hl - hh);
    float cv = 0.5f * (ll + lh - hl - hh);
    float d = 0.5f * (ll - lh - hl + hh);
    float* o = rec + (size_t)bc * 4 * hw + (size_t)(2 * p) * (2 * w) + 2 * q;
    *reinterpret_cast<float2*>(o) = make_float2(a, b);
    *reinterpret_cast<float2*>(o + 2 * w) = make_float2(cv, d);
}

// ---------------------------------------------------------------------------
// Final fused v3: 56x56 output tile, 64x64 x-tile, 256 threads.
// Phases: (1) stage x (float4)  (2) haar butterfly + BASE CONV (bacc in regs)
//         + rec1 prefetch  (3) subband convs -> s_cv (overlaid on dead s_x)
//         (4) inverse haar + combine + store.
// LDS 33.3 KB -> 4 blocks/CU (was 46.5 KB / 3 blocks).
// ---------------------------------------------------------------------------
__global__ __launch_bounds__(256, 4) void final_fused_v3(
    const float* __restrict__ x,
    const float* __restrict__ bw,
    const float* __restrict__ bb,
    const float* __restrict__ bs,
    const float* __restrict__ wt0,
    const float* __restrict__ wsc0,
    const float* __restrict__ rec1,
    float* __restrict__ out)
{
    const int bc = blockIdx.z, c = bc % CC;
    const int t = threadIdx.x;

    __shared__ float s_x[64 * 65];        // phase 3+: reused as s_cv[4][28*29]
    __shared__ float s_sb[4][32 * 33];
    __shared__ float s_wt[4][25];
    __shared__ float s_bw[25];
    __shared__ float s_sc[4];
    float* const s_cv = s_x;              // overlay: 4*812 = 3248 <= 4160 floats

    if (t < 100) { int s = t / 25, k = t % 25; s_wt[s][k] = wt0[(c * 4 + s) * 25 + k]; }
    if (t >= 128 && t < 153) s_bw[t - 128] = bw[c * 25 + (t - 128)];
    if (t >= 192 && t < 196) s_sc[t - 192] = wsc0[c * 4 + (t - 192)];

    // ---- phase 1: stage 64x64 x-tile, float4 global loads ----
    const float* xp = x + (size_t)bc * HH * WW;
    const int gy0 = 56 * blockIdx.y - 4, gx0 = 56 * blockIdx.x - 4;
    for (int idx = t; idx < 1024; idx += 256) {
        int r = idx >> 4, j = idx & 15;
        int gr = gy0 + r, gc = gx0 + 4 * j;
        float4 v = make_float4(0.f, 0.f, 0.f, 0.f);
        if (gr >= 0 && gr < HH && gc >= 0 && gc + 3 < WW)
            v = *(const float4*)(xp + (size_t)gr * WW + gc);
        float* dst = &s_x[r * 65 + 4 * j];
        dst[0] = v.x; dst[1] = v.y; dst[2] = v.z; dst[3] = v.w;
    }
    __syncthreads();

    // ---- phase 2: haar butterfly + base conv (regs) + rec1 prefetch ----
    for (int idx = t; idx < 1024; idx += 256) {
        int sr = idx >> 5, sc2 = idx & 31;
        const float* p0 = &s_x[(2 * sr) * 65 + 2 * sc2];
        float a = p0[0], b = p0[1], cv = p0[65], d = p0[66];
        s_sb[0][sr * 33 + sc2] = 0.5f * (a + b + cv + d);
        s_sb[1][sr * 33 + sc2] = 0.5f * (a - b + cv - d);
        s_sb[2][sr * 33 + sc2] = 0.5f * (a + b - cv - d);
        s_sb[3][sr * 33 + sc2] = 0.5f * (a - b - cv + d);
    }

    const int q4 = t % 56, rb4 = t / 56;    // phase-2/4 mapping (t < 224)
    float bacc[14];
    float rv[7];
    if (t < 224) {
        float w[25];
        #pragma unroll
        for (int k = 0; k < 25; ++k) w[k] = s_bw[k];
        #pragma unroll
        for (int r = 0; r < 14; ++r) bacc[r] = 0.f;
        #pragma unroll
        for (int ri = 0; ri < 18; ++ri) {
            const float* rp = &s_x[(rb4 * 14 + ri + 2) * 65 + q4 + 2];
            float v0 = rp[0], v1 = rp[1], v2 = rp[2], v3 = rp[3], v4 = rp[4];
            #pragma unroll
            for (int ki = 0; ki < 5; ++ki) {
                int r = ri - ki;
                if (r >= 0 && r < 14)
                    bacc[r] += v0 * w[ki * 5] + v1 * w[ki * 5 + 1] + v2 * w[ki * 5 + 2]
                             + v3 * w[ki * 5 + 3] + v4 * w[ki * 5 + 4];
            }
        }
        // prefetch rec1 (consumed in phase 4; latency hides under phase 3)
        const float* recp = rec1 + ((size_t)bc * 112 + 28 * blockIdx.y + rb4 * 7) * 112
                          + 28 * blockIdx.x + (q4 >> 1);
        #pragma unroll
        for (int j = 0; j < 7; ++j) rv[j] = recp[(size_t)j * 112];
    }
    __syncthreads();

    // ---- phase 3: level-0 subband convs -> s_cv (overlaid on s_x) ----
    {
        const int s = t >> 6, u = t & 63;
        if (u < 56) {
            const int q = u % 28, rb = u / 28;
            float w[25];
            #pragma unroll
            for (int k = 0; k < 25; ++k) w[k] = s_wt[s][k];
            const float scale = s_sc[s];
            float acc[14];
            #pragma unroll
            for (int r = 0; r < 14; ++r) acc[r] = 0.f;
            #pragma unroll
            for (int ri = 0; ri < 18; ++ri) {
                const float* rp = &s_sb[s][(rb * 14 + ri) * 33 + q];
                float v0 = rp[0], v1 = rp[1], v2 = rp[2], v3 = rp[3], v4 = rp[4];
                #pragma unroll
                for (int ki = 0; ki < 5; ++ki) {
                    int r = ri - ki;
                    if (r >= 0 && r < 14)
                        acc[r] += v0 * w[ki * 5] + v1 * w[ki * 5 + 1] + v2 * w[ki * 5 + 2]
                                + v3 * w[ki * 5 + 3] + v4 * w[ki * 5 + 4];
                }
            }
            #pragma unroll
            for (int r = 0; r < 14; ++r)
                s_cv[s * 812 + (rb * 14 + r) * 29 + q] = acc[r] * scale;
        }
    }
    __syncthreads();

    // ---- phase 4: inverse haar + combine with base + store ----
    if (t < 224) {
        const float bsc = bs[c], bbv = bb[c];
        const int qs = q4 >> 1;
        const float sx = (q4 & 1) ? -1.f : 1.f;
        float* op = out + ((size_t)bc * HH + 56 * blockIdx.y + rb4 * 14) * WW
                        + 56 * blockIdx.x + q4;
        #pragma unroll
        for (int j = 0; j < 7; ++j) {
            const int p = rb4 * 7 + j;
            float ll = s_cv[0 * 812 + p * 29 + qs] + rv[j];
            float lh = s_cv[1 * 812 + p * 29 + qs];
            float hl = s_cv[2 * 812 + p * 29 + qs];
            float hh = s_cv[3 * 812 + p * 29 + qs];
            float e0 = ll + sx * lh;
            float e1 = hl + sx * hh;
            float top = 0.5f * (e0 + e1);
            float bot = 0.5f * (e0 - e1);
            op[(size_t)(2 * j) * WW]     = bacc[2 * j] * bsc + bbv + top;
            op[(size_t)(2 * j + 1) * WW] = bacc[2 * j + 1] * bsc + bbv + bot;
        }
    }
}

extern "C" void kernel_launch(void* const* d_in, const int* in_sizes, int n_in,
                              void* d_out, int out_size, void* d_ws, size_t ws_size,
                              hipStream_t stream) {
    const float* x          = (const float*)d_in[0];
    const float* base_w     = (const float*)d_in[1];
    const float* base_b     = (const float*)d_in[2];
    const float* base_scale = (const float*)d_in[3];
    const float* wconv_w    = (const float*)d_in[4]; // (3, 384, 25)
    const float* wscale     = (const float*)d_in[5]; // (3, 384)
    float* out = (float*)d_out;
    float* ws  = (float*)d_ws;

    const size_t n1 = (size_t)BB * CC * 4 * 56 * 56;   // coeffs1
    const size_t n2 = (size_t)BB * CC * 4 * 28 * 28;   // coeffs2
    const size_t m1 = (size_t)BB * CC * 112 * 112;     // cur1 / rec1

    float* coeffs1 = ws;
    float* coeffs2 = coeffs1 + n1;
    float* cur1    = coeffs2 + n2;
    float* cur2    = cur1 + m1;

    const int z = BB * CC;

    // level-0 LL (input to level 1)
    {
        int total = BB * CC * 112 * 28;
        haar_ll_kernel<<<(total + 255) / 256, 256, 0, stream>>>(x, cur1);
    }
    // levels 1,2: fused haar + dwconv (column-sliding)
    haar_conv_v2<<<dim3(2, 2, z), 256, 0, stream>>>(
        cur1, coeffs1, cur2, wconv_w + 1 * 384 * 25, wscale + 1 * 384, 112);
    haar_conv_v2<<<dim3(1, 1, z), 256, 0, stream>>>(
        cur2, coeffs2, nullptr, wconv_w + 2 * 384 * 25, wscale + 2 * 384, 56);

    // reconstruction of levels 2,1 (reuse cur buffers)
    {
        int total = BB * CC * 28 * 28;
        ihaar_add_kernel<<<(total + 255) / 256, 256, 0, stream>>>(
            coeffs2, nullptr, cur2, 28, 28, total);   // rec2 (56x56) -> cur2
    }
    {
        int total = BB * CC * 56 * 56;
        ihaar_add_kernel<<<(total + 255) / 256, 256, 0, stream>>>(
            coeffs1, cur2, cur1, 56, 56, total);      // rec1 (112x112) -> cur1
    }

    // fused: base conv + level-0 haar+conv (+rec1) + inverse haar
    final_fused_v3<<<dim3(4, 4, z), 256, 0, stream>>>(
        x, base_w, base_b, base_scale,
        wconv_w + 0 * 384 * 25, wscale + 0 * 384, cur1, out);
}

// Round 6
// 182.712 us; speedup vs baseline: 2.8463x; 1.2111x over previous
//
#include <hip/hip_runtime.h>

#define BB 8
#define CC 96
#define HH 224
#define WW 224

// ---------------------------------------------------------------------------
// Level-1 haar+conv fused with on-the-fly level-0 LL (reads x directly).
// x (B*C,224,224) -> coeffs1 (B*C,4,56,56), cur2 (B*C,56,56)
// Block covers 28x28 of the 56-res output; cur1 tile 64x64 (halo 4) built
// during staging as 2x2 sums of x (128x128 region).
// ---------------------------------------------------------------------------
__global__ __launch_bounds__(256) void haar_conv_l1x(
    const float* __restrict__ x,
    float* __restrict__ coeffs,
    float* __restrict__ raw_ll,
    const float* __restrict__ wt,
    const float* __restrict__ wsc)
{
    const int h2 = 56;
    const int bc = blockIdx.z, c = bc % CC;
    const int t = threadIdx.x;

    __shared__ float s_cur[64 * 65];
    __shared__ float s_sb[4][32 * 33];
    __shared__ float s_wt[4][25];
    __shared__ float s_sc[4];

    if (t < 100) { int s = t / 25, k = t % 25; s_wt[s][k] = wt[(c * 4 + s) * 25 + k]; }
    if (t >= 128 && t < 132) s_sc[t - 128] = wsc[c * 4 + (t - 128)];

    // stage: cur1[r][4g..4g+3] = 0.5 * (2x2 sums) of x rows (2r,2r+1)
    const float* xp = x + (size_t)bc * HH * WW;
    const int gy0x = 112 * blockIdx.y - 8;
    const int gx0x = 112 * blockIdx.x - 8;
    for (int idx = t; idx < 1024; idx += 256) {
        int r = idx >> 4, g = idx & 15;
        int xr = gy0x + 2 * r;
        int xc = gx0x + 8 * g;
        float4 z = make_float4(0.f, 0.f, 0.f, 0.f);
        float4 a0 = z, a1 = z, b0 = z, b1 = z;
        bool r0ok = (unsigned)xr < HH, r1ok = (unsigned)(xr + 1) < HH;
        bool c0ok = (unsigned)xc < WW, c1ok = (unsigned)(xc + 4) < WW;
        const float* row0 = xp + (size_t)xr * WW;
        const float* row1 = row0 + WW;
        if (r0ok && c0ok) a0 = *(const float4*)(row0 + xc);
        if (r0ok && c1ok) a1 = *(const float4*)(row0 + xc + 4);
        if (r1ok && c0ok) b0 = *(const float4*)(row1 + xc);
        if (r1ok && c1ok) b1 = *(const float4*)(row1 + xc + 4);
        float* dst = &s_cur[r * 65 + 4 * g];
        dst[0] = 0.5f * (a0.x + a0.y + b0.x + b0.y);
        dst[1] = 0.5f * (a0.z + a0.w + b0.z + b0.w);
        dst[2] = 0.5f * (a1.x + a1.y + b1.x + b1.y);
        dst[3] = 0.5f * (a1.z + a1.w + b1.z + b1.w);
    }
    __syncthreads();

    for (int idx = t; idx < 1024; idx += 256) {
        int sr = idx >> 5, sc2 = idx & 31;
        const float* p0 = &s_cur[(2 * sr) * 65 + 2 * sc2];
        float a = p0[0], b = p0[1], cv = p0[65], d = p0[66];
        s_sb[0][sr * 33 + sc2] = 0.5f * (a + b + cv + d);
        s_sb[1][sr * 33 + sc2] = 0.5f * (a - b + cv - d);
        s_sb[2][sr * 33 + sc2] = 0.5f * (a + b - cv - d);
        s_sb[3][sr * 33 + sc2] = 0.5f * (a - b - cv + d);
    }
    __syncthreads();

    const int s = t >> 6, u = t & 63;
    if (u < 56) {
        const int q = u % 28, rb = u / 28;
        float w[25];
        #pragma unroll
        for (int k = 0; k < 25; ++k) w[k] = s_wt[s][k];
        const float scale = s_sc[s];
        float acc[14];
        #pragma unroll
        for (int r = 0; r < 14; ++r) acc[r] = 0.f;

        const int p0g = 28 * blockIdx.y + rb * 14;
        const int qg  = 28 * blockIdx.x + q;

        #pragma unroll
        for (int ri = 0; ri < 18; ++ri) {
            const float* rp = &s_sb[s][(rb * 14 + ri) * 33 + q];
            float v0 = rp[0], v1 = rp[1], v2 = rp[2], v3 = rp[3], v4 = rp[4];
            if (s == 0 && ri >= 2 && ri < 16)
                raw_ll[((size_t)bc * h2 + (p0g + ri - 2)) * h2 + qg] = v2;
            #pragma unroll
            for (int ki = 0; ki < 5; ++ki) {
                int r = ri - ki;
                if (r >= 0 && r < 14)
                    acc[r] += v0 * w[ki * 5] + v1 * w[ki * 5 + 1] + v2 * w[ki * 5 + 2]
                            + v3 * w[ki * 5 + 3] + v4 * w[ki * 5 + 4];
            }
        }
        const size_t ob = ((size_t)(bc * 4 + s) * h2 + p0g) * h2 + qg;
        #pragma unroll
        for (int r = 0; r < 14; ++r)
            coeffs[ob + (size_t)r * h2] = acc[r] * scale;
    }
}

// ---------------------------------------------------------------------------
// haar + dwconv, column-sliding (level 2 only now). in = cur2 (56-res).
// ---------------------------------------------------------------------------
__global__ __launch_bounds__(256) void haar_conv_v2(
    const float* __restrict__ in,
    float* __restrict__ coeffs,
    const float* __restrict__ wt,
    const float* __restrict__ wsc,
    int h)
{
    const int h2 = h >> 1;
    const int bc = blockIdx.z, c = bc % CC;
    const int t = threadIdx.x;

    __shared__ float s_x[64 * 65];
    __shared__ float s_sb[4][32 * 33];
    __shared__ float s_wt[4][25];
    __shared__ float s_sc[4];

    if (t < 100) { int s = t / 25, k = t % 25; s_wt[s][k] = wt[(c * 4 + s) * 25 + k]; }
    if (t >= 128 && t < 132) s_sc[t - 128] = wsc[c * 4 + (t - 128)];

    const float* inp = in + (size_t)bc * h * h;
    const int gy0 = 56 * blockIdx.y - 4, gx0 = 56 * blockIdx.x - 4;
    for (int idx = t; idx < 4096; idx += 256) {
        int r = idx >> 6, cl = idx & 63;
        int gr = gy0 + r, gc = gx0 + cl;
        float v = 0.f;
        if (gr >= 0 && gr < h && gc >= 0 && gc < h) v = inp[(size_t)gr * h + gc];
        s_x[r * 65 + cl] = v;
    }
    __syncthreads();

    for (int idx = t; idx < 1024; idx += 256) {
        int sr = idx >> 5, sc2 = idx & 31;
        const float* p0 = &s_x[(2 * sr) * 65 + 2 * sc2];
        float a = p0[0], b = p0[1], cv = p0[65], d = p0[66];
        s_sb[0][sr * 33 + sc2] = 0.5f * (a + b + cv + d);
        s_sb[1][sr * 33 + sc2] = 0.5f * (a - b + cv - d);
        s_sb[2][sr * 33 + sc2] = 0.5f * (a + b - cv - d);
        s_sb[3][sr * 33 + sc2] = 0.5f * (a - b - cv + d);
    }
    __syncthreads();

    const int s = t >> 6, u = t & 63;
    if (u < 56) {
        const int q = u % 28, rb = u / 28;
        float w[25];
        #pragma unroll
        for (int k = 0; k < 25; ++k) w[k] = s_wt[s][k];
        const float scale = s_sc[s];
        float acc[14];
        #pragma unroll
        for (int r = 0; r < 14; ++r) acc[r] = 0.f;

        const int p0g = 28 * blockIdx.y + rb * 14;
        const int qg  = 28 * blockIdx.x + q;

        #pragma unroll
        for (int ri = 0; ri < 18; ++ri) {
            const float* rp = &s_sb[s][(rb * 14 + ri) * 33 + q];
            float v0 = rp[0], v1 = rp[1], v2 = rp[2], v3 = rp[3], v4 = rp[4];
            #pragma unroll
            for (int ki = 0; ki < 5; ++ki) {
                int r = ri - ki;
                if (r >= 0 && r < 14)
                    acc[r] += v0 * w[ki * 5] + v1 * w[ki * 5 + 1] + v2 * w[ki * 5 + 2]
                            + v3 * w[ki * 5 + 3] + v4 * w[ki * 5 + 4];
            }
        }
        const size_t ob = ((size_t)(bc * 4 + s) * h2 + p0g) * h2 + qg;
        #pragma unroll
        for (int r = 0; r < 14; ++r)
            coeffs[ob + (size_t)r * h2] = acc[r] * scale;
    }
}

// ---------------------------------------------------------------------------
// Final fused v4: base conv(x) + L0 haar+conv + FULL reconstruction
// (ihaar2 + ihaar1 + ihaar0) from coeffs1/coeffs2. Reads x,c1,c2; writes out.
// Tile alignment: out 56x56 -> L0 subband 28x28 -> c1 14x14 -> c2 7x7 (no halo:
// ihaar is pointwise per 2x2).
// ---------------------------------------------------------------------------
__global__ __launch_bounds__(256, 4) void final_fused_v4(
    const float* __restrict__ x,
    const float* __restrict__ bw,
    const float* __restrict__ bb,
    const float* __restrict__ bs,
    const float* __restrict__ wt0,
    const float* __restrict__ wsc0,
    const float* __restrict__ c1,   // (B*C,4,56,56)
    const float* __restrict__ c2,   // (B*C,4,28,28)
    float* __restrict__ out)
{
    const int bc = blockIdx.z, c = bc % CC;
    const int t = threadIdx.x;

    __shared__ float s_x[64 * 65];      // phase 3+: overlaid by s_cv[4][28*29]
    __shared__ float s_sb[4][32 * 33];
    __shared__ float s_rec1[28 * 29];
    __shared__ float s_rec2[14 * 15];
    __shared__ float s_wt[4][25];
    __shared__ float s_bw[25];
    __shared__ float s_sc[4];
    float* const s_cv = s_x;            // 4*812 = 3248 <= 4160 floats

    if (t < 100) { int s = t / 25, k = t % 25; s_wt[s][k] = wt0[(c * 4 + s) * 25 + k]; }
    if (t >= 128 && t < 153) s_bw[t - 128] = bw[c * 25 + (t - 128)];
    if (t >= 192 && t < 196) s_sc[t - 192] = wsc0[c * 4 + (t - 192)];

    // ---- issue coeff loads early (latency hides under x staging) ----
    float c2v[4], c1v[4];
    const int p1 = t / 14, q1 = t % 14;
    if (t < 49) {
        const int p2 = t / 7, q2 = t % 7;
        const size_t b2 = (((size_t)bc * 4) * 28 + 7 * blockIdx.y + p2) * 28
                        + 7 * blockIdx.x + q2;
        #pragma unroll
        for (int s = 0; s < 4; ++s) c2v[s] = c2[b2 + (size_t)s * 28 * 28];
    }
    if (t < 196) {
        const size_t b1 = (((size_t)bc * 4) * 56 + 14 * blockIdx.y + p1) * 56
                        + 14 * blockIdx.x + q1;
        #pragma unroll
        for (int s = 0; s < 4; ++s) c1v[s] = c1[b1 + (size_t)s * 56 * 56];
    }

    // ---- phase 1: stage 64x64 x-tile, float4 loads ----
    const float* xp = x + (size_t)bc * HH * WW;
    const int gy0 = 56 * blockIdx.y - 4, gx0 = 56 * blockIdx.x - 4;
    for (int idx = t; idx < 1024; idx += 256) {
        int r = idx >> 4, j = idx & 15;
        int gr = gy0 + r, gc = gx0 + 4 * j;
        float4 v = make_float4(0.f, 0.f, 0.f, 0.f);
        if (gr >= 0 && gr < HH && gc >= 0 && gc + 3 < WW)
            v = *(const float4*)(xp + (size_t)gr * WW + gc);
        float* dst = &s_x[r * 65 + 4 * j];
        dst[0] = v.x; dst[1] = v.y; dst[2] = v.z; dst[3] = v.w;
    }

    // ---- ihaar level 2 (next_ll = 0): c2 -> s_rec2 (14x14) ----
    if (t < 49) {
        const int p2 = t / 7, q2 = t % 7;
        float ll = c2v[0], lh = c2v[1], hl = c2v[2], hh = c2v[3];
        float a  = 0.5f * (ll + lh + hl + hh);
        float b  = 0.5f * (ll - lh + hl - hh);
        float cv = 0.5f * (ll + lh - hl - hh);
        float d  = 0.5f * (ll - lh - hl + hh);
        float* rp = &s_rec2[(2 * p2) * 15 + 2 * q2];
        rp[0] = a; rp[1] = b; rp[15] = cv; rp[16] = d;
    }
    __syncthreads();

    // ---- phase 2: haar butterfly + base conv (regs) + ihaar level 1 ----
    for (int idx = t; idx < 1024; idx += 256) {
        int sr = idx >> 5, sc2 = idx & 31;
        const float* p0 = &s_x[(2 * sr) * 65 + 2 * sc2];
        float a = p0[0], b = p0[1], cv = p0[65], d = p0[66];
        s_sb[0][sr * 33 + sc2] = 0.5f * (a + b + cv + d);
        s_sb[1][sr * 33 + sc2] = 0.5f * (a - b + cv - d);
        s_sb[2][sr * 33 + sc2] = 0.5f * (a + b - cv - d);
        s_sb[3][sr * 33 + sc2] = 0.5f * (a - b - cv + d);
    }

    const int q4 = t % 56, rb4 = t / 56;    // phase-2/4 mapping (t < 224)
    float bacc[14];
    if (t < 224) {
        float w[25];
        #pragma unroll
        for (int k = 0; k < 25; ++k) w[k] = s_bw[k];
        #pragma unroll
        for (int r = 0; r < 14; ++r) bacc[r] = 0.f;
        #pragma unroll
        for (int ri = 0; ri < 18; ++ri) {
            const float* rp = &s_x[(rb4 * 14 + ri + 2) * 65 + q4 + 2];
            float v0 = rp[0], v1 = rp[1], v2 = rp[2], v3 = rp[3], v4 = rp[4];
            #pragma unroll
            for (int ki = 0; ki < 5; ++ki) {
                int r = ri - ki;
                if (r >= 0 && r < 14)
                    bacc[r] += v0 * w[ki * 5] + v1 * w[ki * 5 + 1] + v2 * w[ki * 5 + 2]
                             + v3 * w[ki * 5 + 3] + v4 * w[ki * 5 + 4];
            }
        }
    }
    // ihaar level 1: (c1 with LL += rec2) -> s_rec1 (28x28)
    if (t < 196) {
        float ll = c1v[0] + s_rec2[p1 * 15 + q1];
        float lh = c1v[1], hl = c1v[2], hh = c1v[3];
        float a  = 0.5f * (ll + lh + hl + hh);
        float b  = 0.5f * (ll - lh + hl - hh);
        float cv = 0.5f * (ll + lh - hl - hh);
        float d  = 0.5f * (ll - lh - hl + hh);
        float* rp = &s_rec1[(2 * p1) * 29 + 2 * q1];
        rp[0] = a; rp[1] = b; rp[29] = cv; rp[30] = d;
    }
    __syncthreads();

    // ---- phase 3: level-0 subband convs -> s_cv (overlaid on dead s_x) ----
    {
        const int s = t >> 6, u = t & 63;
        if (u < 56) {
            const int q = u % 28, rb = u / 28;
            float w[25];
            #pragma unroll
            for (int k = 0; k < 25; ++k) w[k] = s_wt[s][k];
            const float scale = s_sc[s];
            float acc[14];
            #pragma unroll
            for (int r = 0; r < 14; ++r) acc[r] = 0.f;
            #pragma unroll
            for (int ri = 0; ri < 18; ++ri) {
                const float* rp = &s_sb[s][(rb * 14 + ri) * 33 + q];
                float v0 = rp[0], v1 = rp[1], v2 = rp[2], v3 = rp[3], v4 = rp[4];
                #pragma unroll
                for (int ki = 0; ki < 5; ++ki) {
                    int r = ri - ki;
                    if (r >= 0 && r < 14)
                        acc[r] += v0 * w[ki * 5] + v1 * w[ki * 5 + 1] + v2 * w[ki * 5 + 2]
                                + v3 * w[ki * 5 + 3] + v4 * w[ki * 5 + 4];
                }
            }
            #pragma unroll
            for (int r = 0; r < 14; ++r)
                s_cv[s * 812 + (rb * 14 + r) * 29 + q] = acc[r] * scale;
        }
    }
    __syncthreads();

    // ---- phase 4: ihaar level 0 + combine with base + store ----
    if (t < 224) {
        const float bsc = bs[c], bbv = bb[c];
        const int qs = q4 >> 1;
        const float sx = (q4 & 1) ? -1.f : 1.f;
        float* op = out + ((size_t)bc * HH + 56 * blockIdx.y + rb4 * 14) * WW
                        + 56 * blockIdx.x + q4;
        #pragma unroll
        for (int j = 0; j < 7; ++j) {
            const int p = rb4 * 7 + j;
            float ll = s_cv[0 * 812 + p * 29 + qs] + s_rec1[p * 29 + qs];
            float lh = s_cv[1 * 812 + p * 29 + qs];
            float hl = s_cv[2 * 812 + p * 29 + qs];
            float hh = s_cv[3 * 812 + p * 29 + qs];
            float e0 = ll + sx * lh;
            float e1 = hl + sx * hh;
            float top = 0.5f * (e0 + e1);
            float bot = 0.5f * (e0 - e1);
            op[(size_t)(2 * j) * WW]     = bacc[2 * j] * bsc + bbv + top;
            op[(size_t)(2 * j + 1) * WW] = bacc[2 * j + 1] * bsc + bbv + bot;
        }
    }
}

extern "C" void kernel_launch(void* const* d_in, const int* in_sizes, int n_in,
                              void* d_out, int out_size, void* d_ws, size_t ws_size,
                              hipStream_t stream) {
    const float* x          = (const float*)d_in[0];
    const float* base_w     = (const float*)d_in[1];
    const float* base_b     = (const float*)d_in[2];
    const float* base_scale = (const float*)d_in[3];
    const float* wconv_w    = (const float*)d_in[4]; // (3, 384, 25)
    const float* wscale     = (const float*)d_in[5]; // (3, 384)
    float* out = (float*)d_out;
    float* ws  = (float*)d_ws;

    const size_t n1 = (size_t)BB * CC * 4 * 56 * 56;   // coeffs1
    const size_t n2 = (size_t)BB * CC * 4 * 28 * 28;   // coeffs2

    float* coeffs1 = ws;
    float* coeffs2 = coeffs1 + n1;
    float* cur2    = coeffs2 + n2;

    const int z = BB * CC;

    // level 1 (fused with on-the-fly level-0 LL): x -> coeffs1, cur2
    haar_conv_l1x<<<dim3(2, 2, z), 256, 0, stream>>>(
        x, coeffs1, cur2, wconv_w + 1 * 384 * 25, wscale + 1 * 384);
    // level 2: cur2 -> coeffs2
    haar_conv_v2<<<dim3(1, 1, z), 256, 0, stream>>>(
        cur2, coeffs2, wconv_w + 2 * 384 * 25, wscale + 2 * 384, 56);
    // final: base conv + L0 haar+conv + full reconstruction
    final_fused_v4<<<dim3(4, 4, z), 256, 0, stream>>>(
        x, base_w, base_b, base_scale,
        wconv_w + 0 * 384 * 25, wscale + 0 * 384, coeffs1, coeffs2, out);
}

// Round 8
// 166.507 us; speedup vs baseline: 3.1233x; 1.0973x over previous
//
#include <hip/hip_runtime.h>

#define BB 8
#define CC 96
#define HH 224
#define WW 224

typedef _Float16 h2 __attribute__((ext_vector_type(2)));
__device__ __forceinline__ h2 u2h(unsigned u) { return __builtin_bit_cast(h2, u); }
// cvt_pkrtz returns __fp16x2; bit-cast its own type straight to unsigned
__device__ __forceinline__ unsigned pkrtz(float a, float b) {
    return __builtin_bit_cast(unsigned, __builtin_amdgcn_cvt_pkrtz(a, b));
}

#if __has_builtin(__builtin_amdgcn_fdot2)
#define FDOT2(a, b, c) __builtin_amdgcn_fdot2((a), (b), (c), false)
#else
#define FDOT2(a, b, c) ((float)(a).x * (float)(b).x + (float)(a).y * (float)(b).y + (c))
#endif

// ---------------------------------------------------------------------------
// Level-1 haar+conv fused with on-the-fly level-0 LL (reads x directly).
// ---------------------------------------------------------------------------
__global__ __launch_bounds__(256) void haar_conv_l1x(
    const float* __restrict__ x,
    float* __restrict__ coeffs,
    float* __restrict__ raw_ll,
    const float* __restrict__ wt,
    const float* __restrict__ wsc)
{
    const int h2v = 56;
    const int bc = blockIdx.z, c = bc % CC;
    const int t = threadIdx.x;

    __shared__ float s_cur[64 * 65];
    __shared__ float s_sb[4][32 * 33];
    __shared__ float s_wt[4][25];
    __shared__ float s_sc[4];

    if (t < 100) { int s = t / 25, k = t % 25; s_wt[s][k] = wt[(c * 4 + s) * 25 + k]; }
    if (t >= 128 && t < 132) s_sc[t - 128] = wsc[c * 4 + (t - 128)];

    const float* xp = x + (size_t)bc * HH * WW;
    const int gy0x = 112 * blockIdx.y - 8;
    const int gx0x = 112 * blockIdx.x - 8;
    for (int idx = t; idx < 1024; idx += 256) {
        int r = idx >> 4, g = idx & 15;
        int xr = gy0x + 2 * r;
        int xc = gx0x + 8 * g;
        float4 z = make_float4(0.f, 0.f, 0.f, 0.f);
        float4 a0 = z, a1 = z, b0 = z, b1 = z;
        bool r0ok = (unsigned)xr < HH, r1ok = (unsigned)(xr + 1) < HH;
        bool c0ok = (unsigned)xc < WW, c1ok = (unsigned)(xc + 4) < WW;
        const float* row0 = xp + (size_t)xr * WW;
        const float* row1 = row0 + WW;
        if (r0ok && c0ok) a0 = *(const float4*)(row0 + xc);
        if (r0ok && c1ok) a1 = *(const float4*)(row0 + xc + 4);
        if (r1ok && c0ok) b0 = *(const float4*)(row1 + xc);
        if (r1ok && c1ok) b1 = *(const float4*)(row1 + xc + 4);
        float* dst = &s_cur[r * 65 + 4 * g];
        dst[0] = 0.5f * (a0.x + a0.y + b0.x + b0.y);
        dst[1] = 0.5f * (a0.z + a0.w + b0.z + b0.w);
        dst[2] = 0.5f * (a1.x + a1.y + b1.x + b1.y);
        dst[3] = 0.5f * (a1.z + a1.w + b1.z + b1.w);
    }
    __syncthreads();

    for (int idx = t; idx < 1024; idx += 256) {
        int sr = idx >> 5, sc2 = idx & 31;
        const float* p0 = &s_cur[(2 * sr) * 65 + 2 * sc2];
        float a = p0[0], b = p0[1], cv = p0[65], d = p0[66];
        s_sb[0][sr * 33 + sc2] = 0.5f * (a + b + cv + d);
        s_sb[1][sr * 33 + sc2] = 0.5f * (a - b + cv - d);
        s_sb[2][sr * 33 + sc2] = 0.5f * (a + b - cv - d);
        s_sb[3][sr * 33 + sc2] = 0.5f * (a - b - cv + d);
    }
    __syncthreads();

    const int s = t >> 6, u = t & 63;
    if (u < 56) {
        const int q = u % 28, rb = u / 28;
        float w[25];
        #pragma unroll
        for (int k = 0; k < 25; ++k) w[k] = s_wt[s][k];
        const float scale = s_sc[s];
        float acc[14];
        #pragma unroll
        for (int r = 0; r < 14; ++r) acc[r] = 0.f;

        const int p0g = 28 * blockIdx.y + rb * 14;
        const int qg  = 28 * blockIdx.x + q;

        #pragma unroll
        for (int ri = 0; ri < 18; ++ri) {
            const float* rp = &s_sb[s][(rb * 14 + ri) * 33 + q];
            float v0 = rp[0], v1 = rp[1], v2 = rp[2], v3 = rp[3], v4 = rp[4];
            if (s == 0 && ri >= 2 && ri < 16)
                raw_ll[((size_t)bc * h2v + (p0g + ri - 2)) * h2v + qg] = v2;
            #pragma unroll
            for (int ki = 0; ki < 5; ++ki) {
                int r = ri - ki;
                if (r >= 0 && r < 14)
                    acc[r] += v0 * w[ki * 5] + v1 * w[ki * 5 + 1] + v2 * w[ki * 5 + 2]
                            + v3 * w[ki * 5 + 3] + v4 * w[ki * 5 + 4];
            }
        }
        const size_t ob = ((size_t)(bc * 4 + s) * h2v + p0g) * h2v + qg;
        #pragma unroll
        for (int r = 0; r < 14; ++r)
            coeffs[ob + (size_t)r * h2v] = acc[r] * scale;
    }
}

// ---------------------------------------------------------------------------
// haar + dwconv, column-sliding (level 2). in = cur2 (56-res).
// ---------------------------------------------------------------------------
__global__ __launch_bounds__(256) void haar_conv_v2(
    const float* __restrict__ in,
    float* __restrict__ coeffs,
    const float* __restrict__ wt,
    const float* __restrict__ wsc,
    int h)
{
    const int h2v = h >> 1;
    const int bc = blockIdx.z, c = bc % CC;
    const int t = threadIdx.x;

    __shared__ float s_x[64 * 65];
    __shared__ float s_sb[4][32 * 33];
    __shared__ float s_wt[4][25];
    __shared__ float s_sc[4];

    if (t < 100) { int s = t / 25, k = t % 25; s_wt[s][k] = wt[(c * 4 + s) * 25 + k]; }
    if (t >= 128 && t < 132) s_sc[t - 128] = wsc[c * 4 + (t - 128)];

    const float* inp = in + (size_t)bc * h * h;
    const int gy0 = 56 * blockIdx.y - 4, gx0 = 56 * blockIdx.x - 4;
    for (int idx = t; idx < 4096; idx += 256) {
        int r = idx >> 6, cl = idx & 63;
        int gr = gy0 + r, gc = gx0 + cl;
        float v = 0.f;
        if (gr >= 0 && gr < h && gc >= 0 && gc < h) v = inp[(size_t)gr * h + gc];
        s_x[r * 65 + cl] = v;
    }
    __syncthreads();

    for (int idx = t; idx < 1024; idx += 256) {
        int sr = idx >> 5, sc2 = idx & 31;
        const float* p0 = &s_x[(2 * sr) * 65 + 2 * sc2];
        float a = p0[0], b = p0[1], cv = p0[65], d = p0[66];
        s_sb[0][sr * 33 + sc2] = 0.5f * (a + b + cv + d);
        s_sb[1][sr * 33 + sc2] = 0.5f * (a - b + cv - d);
        s_sb[2][sr * 33 + sc2] = 0.5f * (a + b - cv - d);
        s_sb[3][sr * 33 + sc2] = 0.5f * (a - b - cv + d);
    }
    __syncthreads();

    const int s = t >> 6, u = t & 63;
    if (u < 56) {
        const int q = u % 28, rb = u / 28;
        float w[25];
        #pragma unroll
        for (int k = 0; k < 25; ++k) w[k] = s_wt[s][k];
        const float scale = s_sc[s];
        float acc[14];
        #pragma unroll
        for (int r = 0; r < 14; ++r) acc[r] = 0.f;

        const int p0g = 28 * blockIdx.y + rb * 14;
        const int qg  = 28 * blockIdx.x + q;

        #pragma unroll
        for (int ri = 0; ri < 18; ++ri) {
            const float* rp = &s_sb[s][(rb * 14 + ri) * 33 + q];
            float v0 = rp[0], v1 = rp[1], v2 = rp[2], v3 = rp[3], v4 = rp[4];
            #pragma unroll
            for (int ki = 0; ki < 5; ++ki) {
                int r = ri - ki;
                if (r >= 0 && r < 14)
                    acc[r] += v0 * w[ki * 5] + v1 * w[ki * 5 + 1] + v2 * w[ki * 5 + 2]
                            + v3 * w[ki * 5 + 3] + v4 * w[ki * 5 + 4];
            }
        }
        const size_t ob = ((size_t)(bc * 4 + s) * h2v + p0g) * h2v + qg;
        #pragma unroll
        for (int r = 0; r < 14; ++r)
            coeffs[ob + (size_t)r * h2v] = acc[r] * scale;
    }
}

// ---------------------------------------------------------------------------
// Final fused v5: fp16 LDS + fdot2 conv core.
// base conv(x) + L0 haar+conv + full reconstruction (ihaar2+1+0).
// LDS 22.1 KB (was 38.4): s_x2/s_sb packed fp16; s_cv (fp16) overlays s_x2.
// Weights pre-folded (base: *base_scale; subband: *0.5*wscale) and stored as
// parity-dependent half2 pairs so each 5-tap row = 3 v_dot2_f32_f16.
// ---------------------------------------------------------------------------
__global__ __launch_bounds__(256, 5) void final_fused_v5(
    const float* __restrict__ x,
    const float* __restrict__ bw,
    const float* __restrict__ bb,
    const float* __restrict__ bs,
    const float* __restrict__ wt0,
    const float* __restrict__ wsc0,
    const float* __restrict__ c1,   // (B*C,4,56,56)
    const float* __restrict__ c2,   // (B*C,4,28,28)
    float* __restrict__ out)
{
    const int bc = blockIdx.z, c = bc % CC;
    const int t = threadIdx.x;

    __shared__ unsigned s_x2[64 * 34];   // h2 x-tile; phase>=3: fp16 s_cv overlay
    __shared__ unsigned s_sb[4 * 544];   // h2 subbands (unscaled butterfly), stride 17
    __shared__ float s_rec1[28 * 29];
    __shared__ float s_rec2[14 * 15];
    __shared__ unsigned s_w2[150];       // [5 knl][2 par][5 row][3] h2
    _Float16* const s_cvh = reinterpret_cast<_Float16*>(s_x2);

    // ---- weight prep: folded, parity-padded half2 pairs ----
    if (t < 50) {
        int par = t & 1, row = (t >> 1) % 5, knl = t / 10;  // 0=base, 1..4 = subband
        float wv[5];
        if (knl == 0) {
            float sc = bs[c];
            #pragma unroll
            for (int j = 0; j < 5; ++j) wv[j] = bw[c * 25 + row * 5 + j] * sc;
        } else {
            int s = knl - 1;
            float sc = 0.5f * wsc0[c * 4 + s];
            #pragma unroll
            for (int j = 0; j < 5; ++j) wv[j] = wt0[(c * 4 + s) * 25 + row * 5 + j] * sc;
        }
        unsigned* dst = &s_w2[((knl * 2 + par) * 5 + row) * 3];
        if (par == 0) {
            dst[0] = pkrtz(wv[0], wv[1]);
            dst[1] = pkrtz(wv[2], wv[3]);
            dst[2] = pkrtz(wv[4], 0.f);
        } else {
            dst[0] = pkrtz(0.f, wv[0]);
            dst[1] = pkrtz(wv[1], wv[2]);
            dst[2] = pkrtz(wv[3], wv[4]);
        }
    }

    // ---- coeff prefetch (latency hides under x staging) ----
    float c2v[4], c1v[4];
    const int p1 = t / 14, q1 = t % 14;
    if (t < 49) {
        const int p2 = t / 7, q2 = t % 7;
        const size_t b2 = (((size_t)bc * 4) * 28 + 7 * blockIdx.y + p2) * 28
                        + 7 * blockIdx.x + q2;
        #pragma unroll
        for (int s = 0; s < 4; ++s) c2v[s] = c2[b2 + (size_t)s * 28 * 28];
    }
    if (t < 196) {
        const size_t b1 = (((size_t)bc * 4) * 56 + 14 * blockIdx.y + p1) * 56
                        + 14 * blockIdx.x + q1;
        #pragma unroll
        for (int s = 0; s < 4; ++s) c1v[s] = c1[b1 + (size_t)s * 56 * 56];
    }

    // ---- phase 1: stage 64x64 x-tile as packed fp16 ----
    const float* xp = x + (size_t)bc * HH * WW;
    const int gy0 = 56 * blockIdx.y - 4, gx0 = 56 * blockIdx.x - 4;
    for (int idx = t; idx < 1024; idx += 256) {
        int r = idx >> 4, j = idx & 15;
        int gr = gy0 + r, gc = gx0 + 4 * j;
        float4 v = make_float4(0.f, 0.f, 0.f, 0.f);
        if (gr >= 0 && gr < HH && gc >= 0 && gc + 3 < WW)
            v = *(const float4*)(xp + (size_t)gr * WW + gc);
        uint2 pp;
        pp.x = pkrtz(v.x, v.y);
        pp.y = pkrtz(v.z, v.w);
        *(uint2*)&s_x2[r * 34 + 2 * j] = pp;   // even dword -> 8B aligned
    }

    // ---- ihaar level 2 (next_ll = 0): c2 -> s_rec2 (14x14) ----
    if (t < 49) {
        const int p2 = t / 7, q2 = t % 7;
        float ll = c2v[0], lh = c2v[1], hl = c2v[2], hh = c2v[3];
        float a  = 0.5f * (ll + lh + hl + hh);
        float b  = 0.5f * (ll - lh + hl - hh);
        float cv = 0.5f * (ll + lh - hl - hh);
        float d  = 0.5f * (ll - lh - hl + hh);
        float* rp = &s_rec2[(2 * p2) * 15 + 2 * q2];
        rp[0] = a; rp[1] = b; rp[15] = cv; rp[16] = d;
    }
    __syncthreads();

    // ---- phase 2a: haar butterfly (unscaled; 0.5 folded into weights) ----
    for (int idx = t; idx < 512; idx += 256) {
        int sr = idx >> 4, g = idx & 15;
        uint2 tp = *(const uint2*)&s_x2[(2 * sr) * 34 + 2 * g];
        uint2 bt = *(const uint2*)&s_x2[(2 * sr + 1) * 34 + 2 * g];
        h2 t0 = u2h(tp.x), t1 = u2h(tp.y), b0 = u2h(bt.x), b1 = u2h(bt.y);
        float a0 = t0.x, e0 = t0.y, cc0 = b0.x, f0 = b0.y;
        float a1 = t1.x, e1 = t1.y, cc1 = b1.x, f1 = b1.y;
        float P0 = a0 + e0, M0 = a0 - e0, R0 = cc0 + f0, Q0 = cc0 - f0;
        float P1 = a1 + e1, M1 = a1 - e1, R1 = cc1 + f1, Q1 = cc1 - f1;
        s_sb[0 * 544 + sr * 17 + g] = pkrtz(P0 + R0, P1 + R1);
        s_sb[1 * 544 + sr * 17 + g] = pkrtz(M0 + Q0, M1 + Q1);
        s_sb[2 * 544 + sr * 17 + g] = pkrtz(P0 - R0, P1 - R1);
        s_sb[3 * 544 + sr * 17 + g] = pkrtz(M0 - Q0, M1 - Q1);
    }

    // ---- phase 2b: base conv via fdot2 (bacc in regs) ----
    const int q4 = t % 56, rb4 = t / 56;
    float bacc[14];
    if (t < 224) {
        const int par = q4 & 1, d0 = (q4 + 2) >> 1;
        h2 w[5][3];
        {
            const unsigned* wp = &s_w2[(par * 5) * 3];
            #pragma unroll
            for (int ki = 0; ki < 5; ++ki)
                #pragma unroll
                for (int m = 0; m < 3; ++m) w[ki][m] = u2h(wp[ki * 3 + m]);
        }
        #pragma unroll
        for (int r = 0; r < 14; ++r) bacc[r] = 0.f;
        #pragma unroll
        for (int ri = 0; ri < 18; ++ri) {
            const unsigned* rp = &s_x2[(rb4 * 14 + ri + 2) * 34 + d0];
            h2 g0 = u2h(rp[0]), g1 = u2h(rp[1]), g2 = u2h(rp[2]);
            #pragma unroll
            for (int ki = 0; ki < 5; ++ki) {
                int r = ri - ki;
                if (r >= 0 && r < 14)
                    bacc[r] = FDOT2(g0, w[ki][0],
                              FDOT2(g1, w[ki][1],
                              FDOT2(g2, w[ki][2], bacc[r])));
            }
        }
    }
    // ihaar level 1: (c1 with LL += rec2) -> s_rec1 (28x28)
    if (t < 196) {
        float ll = c1v[0] + s_rec2[p1 * 15 + q1];
        float lh = c1v[1], hl = c1v[2], hh = c1v[3];
        float a  = 0.5f * (ll + lh + hl + hh);
        float b  = 0.5f * (ll - lh + hl - hh);
        float cv = 0.5f * (ll + lh - hl - hh);
        float d  = 0.5f * (ll - lh - hl + hh);
        float* rp = &s_rec1[(2 * p1) * 29 + 2 * q1];
        rp[0] = a; rp[1] = b; rp[29] = cv; rp[30] = d;
    }
    __syncthreads();

    // ---- phase 3: subband convs via fdot2 -> fp16 s_cv (overlaid on s_x2) ----
    {
        const int s = t >> 6, u = t & 63;
        if (u < 56) {
            const int q = u % 28, rb = u / 28;
            const int par = q & 1, d0 = q >> 1;
            h2 w[5][3];
            {
                const unsigned* wp = &s_w2[(((1 + s) * 2 + par) * 5) * 3];
                #pragma unroll
                for (int ki = 0; ki < 5; ++ki)
                    #pragma unroll
                    for (int m = 0; m < 3; ++m) w[ki][m] = u2h(wp[ki * 3 + m]);
            }
            float acc[14];
            #pragma unroll
            for (int r = 0; r < 14; ++r) acc[r] = 0.f;
            #pragma unroll
            for (int ri = 0; ri < 18; ++ri) {
                const unsigned* rp = &s_sb[s * 544 + (rb * 14 + ri) * 17 + d0];
                h2 g0 = u2h(rp[0]), g1 = u2h(rp[1]), g2 = u2h(rp[2]);
                #pragma unroll
                for (int ki = 0; ki < 5; ++ki) {
                    int r = ri - ki;
                    if (r >= 0 && r < 14)
                        acc[r] = FDOT2(g0, w[ki][0],
                                 FDOT2(g1, w[ki][1],
                                 FDOT2(g2, w[ki][2], acc[r])));
                }
            }
            #pragma unroll
            for (int r = 0; r < 14; ++r)
                s_cvh[(s * 28 + rb * 14 + r) * 29 + q] = (_Float16)acc[r];
        }
    }
    __syncthreads();

    // ---- phase 4: ihaar level 0 + combine with base + store ----
    if (t < 224) {
        const float bbv = bb[c];
        const int qs = q4 >> 1;
        const float sx = (q4 & 1) ? -1.f : 1.f;
        float* op = out + ((size_t)bc * HH + 56 * blockIdx.y + rb4 * 14) * WW
                        + 56 * blockIdx.x + q4;
        #pragma unroll
        for (int j = 0; j < 7; ++j) {
            const int p = rb4 * 7 + j;
            float ll = (float)s_cvh[(0 * 28 + p) * 29 + qs] + s_rec1[p * 29 + qs];
            float lh = (float)s_cvh[(1 * 28 + p) * 29 + qs];
            float hl = (float)s_cvh[(2 * 28 + p) * 29 + qs];
            float hh = (float)s_cvh[(3 * 28 + p) * 29 + qs];
            float e0 = ll + sx * lh;
            float e1 = hl + sx * hh;
            float top = 0.5f * (e0 + e1);
            float bot = 0.5f * (e0 - e1);
            op[(size_t)(2 * j) * WW]     = bacc[2 * j]     + bbv + top;
            op[(size_t)(2 * j + 1) * WW] = bacc[2 * j + 1] + bbv + bot;
        }
    }
}

extern "C" void kernel_launch(void* const* d_in, const int* in_sizes, int n_in,
                              void* d_out, int out_size, void* d_ws, size_t ws_size,
                              hipStream_t stream) {
    const float* x          = (const float*)d_in[0];
    const float* base_w     = (const float*)d_in[1];
    const float* base_b     = (const float*)d_in[2];
    const float* base_scale = (const float*)d_in[3];
    const float* wconv_w    = (const float*)d_in[4]; // (3, 384, 25)
    const float* wscale     = (const float*)d_in[5]; // (3, 384)
    float* out = (float*)d_out;
    float* ws  = (float*)d_ws;

    const size_t n1 = (size_t)BB * CC * 4 * 56 * 56;   // coeffs1
    const size_t n2 = (size_t)BB * CC * 4 * 28 * 28;   // coeffs2

    float* coeffs1 = ws;
    float* coeffs2 = coeffs1 + n1;
    float* cur2    = coeffs2 + n2;

    const int z = BB * CC;

    // level 1 (fused with on-the-fly level-0 LL): x -> coeffs1, cur2
    haar_conv_l1x<<<dim3(2, 2, z), 256, 0, stream>>>(
        x, coeffs1, cur2, wconv_w + 1 * 384 * 25, wscale + 1 * 384);
    // level 2: cur2 -> coeffs2
    haar_conv_v2<<<dim3(1, 1, z), 256, 0, stream>>>(
        cur2, coeffs2, wconv_w + 2 * 384 * 25, wscale + 2 * 384, 56);
    // final: base conv + L0 haar+conv + full reconstruction (fp16/fdot2 core)
    final_fused_v5<<<dim3(4, 4, z), 256, 0, stream>>>(
        x, base_w, base_b, base_scale,
        wconv_w + 0 * 384 * 25, wscale + 0 * 384, coeffs1, coeffs2, out);
}

// Round 9
// 147.841 us; speedup vs baseline: 3.5177x; 1.1263x over previous
//
#include <hip/hip_runtime.h>

#define BB 8
#define CC 96
#define HH 224
#define WW 224

typedef _Float16 h2 __attribute__((ext_vector_type(2)));
__device__ __forceinline__ h2 u2h(unsigned u) { return __builtin_bit_cast(h2, u); }
__device__ __forceinline__ unsigned pkrtz(float a, float b) {
    return __builtin_bit_cast(unsigned, __builtin_amdgcn_cvt_pkrtz(a, b));
}

#if __has_builtin(__builtin_amdgcn_fdot2)
#define FDOT2(a, b, c) __builtin_amdgcn_fdot2((a), (b), (c), false)
#else
#define FDOT2(a, b, c) ((float)(a).x * (float)(b).x + (float)(a).y * (float)(b).y + (c))
#endif

// ---------------------------------------------------------------------------
// levels_fused: ONE block per (b,c). Computes levels 1 and 2 entirely in LDS.
//   x (224x224 fp32) --2x2 LL--> cur1 (112x112 fp16, exact, no halo)
//   cur1 --butterfly--> sb1 (4x 56x56 +2 halo, fp16)  [+ cur2 = 0.5*(P+R)]
//   sb1 --fdot2 conv--> c1 (global, fp32)
//   cur2 --butterfly--> sb2 (4x 28x28 +2 halo) --fdot2 conv--> c2 (global)
// Weights folded with 0.5*wscale (butterflies stored unscaled = 2x subband).
// LDS ~72 KB -> 2 blocks/CU, 512 threads (16 waves/CU).
// ---------------------------------------------------------------------------
__global__ __launch_bounds__(512, 4) void levels_fused(
    const float* __restrict__ x,
    float* __restrict__ c1,        // (B*C,4,56,56)
    float* __restrict__ c2,        // (B*C,4,28,28)
    const float* __restrict__ wt1, const float* __restrict__ ws1,
    const float* __restrict__ wt2, const float* __restrict__ ws2)
{
    const int bc = blockIdx.x, c = bc % CC;
    const int t = threadIdx.x;

    __shared__ unsigned s_c1[112 * 58];      // cur1 fp16, 56 data dw + pad (even stride)
    __shared__ unsigned s_sb1[4 * 60 * 31];  // L1 subbands, rows 60 (2 halo), 30 dw data
    __shared__ unsigned s_cur2[56 * 30];     // cur2 fp16, 28 data dw (even stride)
    __shared__ unsigned s_sb2[4 * 32 * 17];  // L2 subbands, rows 32, 16 dw data
    __shared__ unsigned s_w2[240];           // [2 lvl][4 band][2 par][5 row][3] h2

    // zero subband arrays (halo must be exactly 0 = SAME padding)
    for (int i = t; i < 4 * 60 * 31; i += 512) s_sb1[i] = 0;
    for (int i = t; i < 4 * 32 * 17; i += 512) s_sb2[i] = 0;

    // folded weights: 0.5 * wscale * w, parity-padded half2 triplets
    if (t < 80) {
        int knl = t / 10;                    // 0..3 = level1 bands, 4..7 = level2
        int par = t & 1, row = (t % 10) >> 1;
        int lvl = knl >> 2, s = knl & 3;
        const float* wt  = lvl ? wt2 : wt1;
        const float* wsc = lvl ? ws2 : ws1;
        float sc = 0.5f * wsc[c * 4 + s];
        float wv[5];
        #pragma unroll
        for (int j = 0; j < 5; ++j) wv[j] = wt[(c * 4 + s) * 25 + row * 5 + j] * sc;
        unsigned* dst = &s_w2[(knl * 2 + par) * 15 + row * 3];
        if (par == 0) {
            dst[0] = pkrtz(wv[0], wv[1]);
            dst[1] = pkrtz(wv[2], wv[3]);
            dst[2] = pkrtz(wv[4], 0.f);
        } else {
            dst[0] = pkrtz(0.f, wv[0]);
            dst[1] = pkrtz(wv[1], wv[2]);
            dst[2] = pkrtz(wv[3], wv[4]);
        }
    }

    // ---- phase A: stage cur1 = level-0 LL straight from x (coalesced) ----
    const float* xp = x + (size_t)bc * HH * WW;
    for (int idx = t; idx < 112 * 56; idx += 512) {
        int r = idx / 56, g = idx % 56;
        const float* r0 = xp + (size_t)(2 * r) * WW + 4 * g;
        const float* r1 = r0 + WW;
        float4 a = *(const float4*)r0;
        float4 b = *(const float4*)r1;
        s_c1[r * 58 + g] = pkrtz(0.5f * (a.x + a.y + b.x + b.y),
                                 0.5f * (a.z + a.w + b.z + b.w));
    }
    __syncthreads();

    // ---- phase B: butterfly cur1 -> sb1 (+ cur2) ----
    for (int idx = t; idx < 56 * 28; idx += 512) {
        int sr = idx / 28, sc2 = idx % 28;
        uint2 tp = *(const uint2*)&s_c1[(2 * sr) * 58 + 2 * sc2];
        uint2 bt = *(const uint2*)&s_c1[(2 * sr + 1) * 58 + 2 * sc2];
        h2 t0 = u2h(tp.x), t1 = u2h(tp.y), b0 = u2h(bt.x), b1 = u2h(bt.y);
        float P0 = (float)t0.x + (float)t0.y, M0 = (float)t0.x - (float)t0.y;
        float R0 = (float)b0.x + (float)b0.y, Q0 = (float)b0.x - (float)b0.y;
        float P1 = (float)t1.x + (float)t1.y, M1 = (float)t1.x - (float)t1.y;
        float R1 = (float)b1.x + (float)b1.y, Q1 = (float)b1.x - (float)b1.y;
        int o = (sr + 2) * 31 + (sc2 + 1);
        s_sb1[0 * 1860 + o] = pkrtz(P0 + R0, P1 + R1);
        s_sb1[1 * 1860 + o] = pkrtz(M0 + Q0, M1 + Q1);
        s_sb1[2 * 1860 + o] = pkrtz(P0 - R0, P1 - R1);
        s_sb1[3 * 1860 + o] = pkrtz(M0 - Q0, M1 - Q1);
        s_cur2[sr * 30 + sc2] = pkrtz(0.5f * (P0 + R0), 0.5f * (P1 + R1));
    }
    __syncthreads();

    // ---- phase C1: butterfly cur2 -> sb2 (small) ----
    if (t < 28 * 14) {
        int sr = t / 14, sc2 = t % 14;
        uint2 tp = *(const uint2*)&s_cur2[(2 * sr) * 30 + 2 * sc2];
        uint2 bt = *(const uint2*)&s_cur2[(2 * sr + 1) * 30 + 2 * sc2];
        h2 t0 = u2h(tp.x), t1 = u2h(tp.y), b0 = u2h(bt.x), b1 = u2h(bt.y);
        float P0 = (float)t0.x + (float)t0.y, M0 = (float)t0.x - (float)t0.y;
        float R0 = (float)b0.x + (float)b0.y, Q0 = (float)b0.x - (float)b0.y;
        float P1 = (float)t1.x + (float)t1.y, M1 = (float)t1.x - (float)t1.y;
        float R1 = (float)b1.x + (float)b1.y, Q1 = (float)b1.x - (float)b1.y;
        int o = (sr + 2) * 17 + (sc2 + 1);
        s_sb2[0 * 544 + o] = pkrtz(P0 + R0, P1 + R1);
        s_sb2[1 * 544 + o] = pkrtz(M0 + Q0, M1 + Q1);
        s_sb2[2 * 544 + o] = pkrtz(P0 - R0, P1 - R1);
        s_sb2[3 * 544 + o] = pkrtz(M0 - Q0, M1 - Q1);
    }

    // ---- phase C2: L1 conv (fdot2, 28-tall columns) -> c1 global ----
    {
        const int s = t >> 7, lane = t & 127;
        const int q = lane & 63, half = lane >> 6;
        if (q < 56) {
            const int par = q & 1, d0 = q >> 1, ps = half * 28;
            h2 w[5][3];
            {
                const unsigned* wp = &s_w2[(s * 2 + par) * 15];
                #pragma unroll
                for (int ki = 0; ki < 5; ++ki)
                    #pragma unroll
                    for (int m = 0; m < 3; ++m) w[ki][m] = u2h(wp[ki * 3 + m]);
            }
            float acc[28];
            #pragma unroll
            for (int r = 0; r < 28; ++r) acc[r] = 0.f;
            #pragma unroll
            for (int ri = 0; ri < 32; ++ri) {
                const unsigned* rp = &s_sb1[s * 1860 + (ps + ri) * 31 + d0];
                h2 g0 = u2h(rp[0]), g1 = u2h(rp[1]), g2 = u2h(rp[2]);
                #pragma unroll
                for (int ki = 0; ki < 5; ++ki) {
                    int r = ri - ki;
                    if (r >= 0 && r < 28)
                        acc[r] = FDOT2(g0, w[ki][0],
                                 FDOT2(g1, w[ki][1],
                                 FDOT2(g2, w[ki][2], acc[r])));
                }
            }
            const size_t ob = ((size_t)(bc * 4 + s) * 56 + ps) * 56 + q;
            #pragma unroll
            for (int r = 0; r < 28; ++r)
                c1[ob + (size_t)r * 56] = acc[r];
        }
    }
    __syncthreads();

    // ---- phase D: L2 conv -> c2 global ----
    if (t < 112) {
        const int s = t / 28, q = t % 28;
        const int par = q & 1, d0 = q >> 1;
        h2 w[5][3];
        {
            const unsigned* wp = &s_w2[((4 + s) * 2 + par) * 15];
            #pragma unroll
            for (int ki = 0; ki < 5; ++ki)
                #pragma unroll
                for (int m = 0; m < 3; ++m) w[ki][m] = u2h(wp[ki * 3 + m]);
        }
        float acc[28];
        #pragma unroll
        for (int r = 0; r < 28; ++r) acc[r] = 0.f;
        #pragma unroll
        for (int ri = 0; ri < 32; ++ri) {
            const unsigned* rp = &s_sb2[s * 544 + ri * 17 + d0];
            h2 g0 = u2h(rp[0]), g1 = u2h(rp[1]), g2 = u2h(rp[2]);
            #pragma unroll
            for (int ki = 0; ki < 5; ++ki) {
                int r = ri - ki;
                if (r >= 0 && r < 28)
                    acc[r] = FDOT2(g0, w[ki][0],
                             FDOT2(g1, w[ki][1],
                             FDOT2(g2, w[ki][2], acc[r])));
            }
        }
        const size_t ob = (size_t)(bc * 4 + s) * 28 * 28 + q;
        #pragma unroll
        for (int r = 0; r < 28; ++r)
            c2[ob + (size_t)r * 28] = acc[r];
    }
}

// ---------------------------------------------------------------------------
// Final fused v5 (unchanged core): fp16 LDS + fdot2; base conv + L0 haar+conv
// + full reconstruction. min-waves bumped to 7 (LDS 22.5K allows 7 blocks/CU).
// ---------------------------------------------------------------------------
__global__ __launch_bounds__(256, 7) void final_fused_v5(
    const float* __restrict__ x,
    const float* __restrict__ bw,
    const float* __restrict__ bb,
    const float* __restrict__ bs,
    const float* __restrict__ wt0,
    const float* __restrict__ wsc0,
    const float* __restrict__ c1,   // (B*C,4,56,56)
    const float* __restrict__ c2,   // (B*C,4,28,28)
    float* __restrict__ out)
{
    const int bc = blockIdx.z, c = bc % CC;
    const int t = threadIdx.x;

    __shared__ unsigned s_x2[64 * 34];   // h2 x-tile; phase>=3: fp16 s_cv overlay
    __shared__ unsigned s_sb[4 * 544];   // h2 subbands (unscaled butterfly), stride 17
    __shared__ float s_rec1[28 * 29];
    __shared__ float s_rec2[14 * 15];
    __shared__ unsigned s_w2[150];       // [5 knl][2 par][5 row][3] h2
    _Float16* const s_cvh = reinterpret_cast<_Float16*>(s_x2);

    if (t < 50) {
        int par = t & 1, row = (t >> 1) % 5, knl = t / 10;  // 0=base, 1..4 = subband
        float wv[5];
        if (knl == 0) {
            float sc = bs[c];
            #pragma unroll
            for (int j = 0; j < 5; ++j) wv[j] = bw[c * 25 + row * 5 + j] * sc;
        } else {
            int s = knl - 1;
            float sc = 0.5f * wsc0[c * 4 + s];
            #pragma unroll
            for (int j = 0; j < 5; ++j) wv[j] = wt0[(c * 4 + s) * 25 + row * 5 + j] * sc;
        }
        unsigned* dst = &s_w2[((knl * 2 + par) * 5 + row) * 3];
        if (par == 0) {
            dst[0] = pkrtz(wv[0], wv[1]);
            dst[1] = pkrtz(wv[2], wv[3]);
            dst[2] = pkrtz(wv[4], 0.f);
        } else {
            dst[0] = pkrtz(0.f, wv[0]);
            dst[1] = pkrtz(wv[1], wv[2]);
            dst[2] = pkrtz(wv[3], wv[4]);
        }
    }

    float c2v[4], c1v[4];
    const int p1 = t / 14, q1 = t % 14;
    if (t < 49) {
        const int p2 = t / 7, q2 = t % 7;
        const size_t b2 = (((size_t)bc * 4) * 28 + 7 * blockIdx.y + p2) * 28
                        + 7 * blockIdx.x + q2;
        #pragma unroll
        for (int s = 0; s < 4; ++s) c2v[s] = c2[b2 + (size_t)s * 28 * 28];
    }
    if (t < 196) {
        const size_t b1 = (((size_t)bc * 4) * 56 + 14 * blockIdx.y + p1) * 56
                        + 14 * blockIdx.x + q1;
        #pragma unroll
        for (int s = 0; s < 4; ++s) c1v[s] = c1[b1 + (size_t)s * 56 * 56];
    }

    const float* xp = x + (size_t)bc * HH * WW;
    const int gy0 = 56 * blockIdx.y - 4, gx0 = 56 * blockIdx.x - 4;
    for (int idx = t; idx < 1024; idx += 256) {
        int r = idx >> 4, j = idx & 15;
        int gr = gy0 + r, gc = gx0 + 4 * j;
        float4 v = make_float4(0.f, 0.f, 0.f, 0.f);
        if (gr >= 0 && gr < HH && gc >= 0 && gc + 3 < WW)
            v = *(const float4*)(xp + (size_t)gr * WW + gc);
        uint2 pp;
        pp.x = pkrtz(v.x, v.y);
        pp.y = pkrtz(v.z, v.w);
        *(uint2*)&s_x2[r * 34 + 2 * j] = pp;
    }

    if (t < 49) {
        const int p2 = t / 7, q2 = t % 7;
        float ll = c2v[0], lh = c2v[1], hl = c2v[2], hh = c2v[3];
        float a  = 0.5f * (ll + lh + hl + hh);
        float b  = 0.5f * (ll - lh + hl - hh);
        float cv = 0.5f * (ll + lh - hl - hh);
        float d  = 0.5f * (ll - lh - hl + hh);
        float* rp = &s_rec2[(2 * p2) * 15 + 2 * q2];
        rp[0] = a; rp[1] = b; rp[15] = cv; rp[16] = d;
    }
    __syncthreads();

    for (int idx = t; idx < 512; idx += 256) {
        int sr = idx >> 4, g = idx & 15;
        uint2 tp = *(const uint2*)&s_x2[(2 * sr) * 34 + 2 * g];
        uint2 bt = *(const uint2*)&s_x2[(2 * sr + 1) * 34 + 2 * g];
        h2 t0 = u2h(tp.x), t1 = u2h(tp.y), b0 = u2h(bt.x), b1 = u2h(bt.y);
        float a0 = t0.x, e0 = t0.y, cc0 = b0.x, f0 = b0.y;
        float a1 = t1.x, e1 = t1.y, cc1 = b1.x, f1 = b1.y;
        float P0 = a0 + e0, M0 = a0 - e0, R0 = cc0 + f0, Q0 = cc0 - f0;
        float P1 = a1 + e1, M1 = a1 - e1, R1 = cc1 + f1, Q1 = cc1 - f1;
        s_sb[0 * 544 + sr * 17 + g] = pkrtz(P0 + R0, P1 + R1);
        s_sb[1 * 544 + sr * 17 + g] = pkrtz(M0 + Q0, M1 + Q1);
        s_sb[2 * 544 + sr * 17 + g] = pkrtz(P0 - R0, P1 - R1);
        s_sb[3 * 544 + sr * 17 + g] = pkrtz(M0 - Q0, M1 - Q1);
    }

    const int q4 = t % 56, rb4 = t / 56;
    float bacc[14];
    if (t < 224) {
        const int par = q4 & 1, d0 = (q4 + 2) >> 1;
        h2 w[5][3];
        {
            const unsigned* wp = &s_w2[(par * 5) * 3];
            #pragma unroll
            for (int ki = 0; ki < 5; ++ki)
                #pragma unroll
                for (int m = 0; m < 3; ++m) w[ki][m] = u2h(wp[ki * 3 + m]);
        }
        #pragma unroll
        for (int r = 0; r < 14; ++r) bacc[r] = 0.f;
        #pragma unroll
        for (int ri = 0; ri < 18; ++ri) {
            const unsigned* rp = &s_x2[(rb4 * 14 + ri + 2) * 34 + d0];
            h2 g0 = u2h(rp[0]), g1 = u2h(rp[1]), g2 = u2h(rp[2]);
            #pragma unroll
            for (int ki = 0; ki < 5; ++ki) {
                int r = ri - ki;
                if (r >= 0 && r < 14)
                    bacc[r] = FDOT2(g0, w[ki][0],
                              FDOT2(g1, w[ki][1],
                              FDOT2(g2, w[ki][2], bacc[r])));
            }
        }
    }
    if (t < 196) {
        float ll = c1v[0] + s_rec2[p1 * 15 + q1];
        float lh = c1v[1], hl = c1v[2], hh = c1v[3];
        float a  = 0.5f * (ll + lh + hl + hh);
        float b  = 0.5f * (ll - lh + hl - hh);
        float cv = 0.5f * (ll + lh - hl - hh);
        float d  = 0.5f * (ll - lh - hl + hh);
        float* rp = &s_rec1[(2 * p1) * 29 + 2 * q1];
        rp[0] = a; rp[1] = b; rp[29] = cv; rp[30] = d;
    }
    __syncthreads();

    {
        const int s = t >> 6, u = t & 63;
        if (u < 56) {
            const int q = u % 28, rb = u / 28;
            const int par = q & 1, d0 = q >> 1;
            h2 w[5][3];
            {
                const unsigned* wp = &s_w2[(((1 + s) * 2 + par) * 5) * 3];
                #pragma unroll
                for (int ki = 0; ki < 5; ++ki)
                    #pragma unroll
                    for (int m = 0; m < 3; ++m) w[ki][m] = u2h(wp[ki * 3 + m]);
            }
            float acc[14];
            #pragma unroll
            for (int r = 0; r < 14; ++r) acc[r] = 0.f;
            #pragma unroll
            for (int ri = 0; ri < 18; ++ri) {
                const unsigned* rp = &s_sb[s * 544 + (rb * 14 + ri) * 17 + d0];
                h2 g0 = u2h(rp[0]), g1 = u2h(rp[1]), g2 = u2h(rp[2]);
                #pragma unroll
                for (int ki = 0; ki < 5; ++ki) {
                    int r = ri - ki;
                    if (r >= 0 && r < 14)
                        acc[r] = FDOT2(g0, w[ki][0],
                                 FDOT2(g1, w[ki][1],
                                 FDOT2(g2, w[ki][2], acc[r])));
                }
            }
            #pragma unroll
            for (int r = 0; r < 14; ++r)
                s_cvh[(s * 28 + rb * 14 + r) * 29 + q] = (_Float16)acc[r];
        }
    }
    __syncthreads();

    if (t < 224) {
        const float bbv = bb[c];
        const int qs = q4 >> 1;
        const float sx = (q4 & 1) ? -1.f : 1.f;
        float* op = out + ((size_t)bc * HH + 56 * blockIdx.y + rb4 * 14) * WW
                        + 56 * blockIdx.x + q4;
        #pragma unroll
        for (int j = 0; j < 7; ++j) {
            const int p = rb4 * 7 + j;
            float ll = (float)s_cvh[(0 * 28 + p) * 29 + qs] + s_rec1[p * 29 + qs];
            float lh = (float)s_cvh[(1 * 28 + p) * 29 + qs];
            float hl = (float)s_cvh[(2 * 28 + p) * 29 + qs];
            float hh = (float)s_cvh[(3 * 28 + p) * 29 + qs];
            float e0 = ll + sx * lh;
            float e1 = hl + sx * hh;
            float top = 0.5f * (e0 + e1);
            float bot = 0.5f * (e0 - e1);
            op[(size_t)(2 * j) * WW]     = bacc[2 * j]     + bbv + top;
            op[(size_t)(2 * j + 1) * WW] = bacc[2 * j + 1] + bbv + bot;
        }
    }
}

extern "C" void kernel_launch(void* const* d_in, const int* in_sizes, int n_in,
                              void* d_out, int out_size, void* d_ws, size_t ws_size,
                              hipStream_t stream) {
    const float* x          = (const float*)d_in[0];
    const float* base_w     = (const float*)d_in[1];
    const float* base_b     = (const float*)d_in[2];
    const float* base_scale = (const float*)d_in[3];
    const float* wconv_w    = (const float*)d_in[4]; // (3, 384, 25)
    const float* wscale     = (const float*)d_in[5]; // (3, 384)
    float* out = (float*)d_out;
    float* ws  = (float*)d_ws;

    const size_t n1 = (size_t)BB * CC * 4 * 56 * 56;   // coeffs1

    float* coeffs1 = ws;
    float* coeffs2 = coeffs1 + n1;

    const int z = BB * CC;

    // levels 1+2 fully fused, one block per (b,c)
    levels_fused<<<z, 512, 0, stream>>>(
        x, coeffs1, coeffs2,
        wconv_w + 1 * 384 * 25, wscale + 1 * 384,
        wconv_w + 2 * 384 * 25, wscale + 2 * 384);
    // final: base conv + L0 haar+conv + full reconstruction
    final_fused_v5<<<dim3(4, 4, z), 256, 0, stream>>>(
        x, base_w, base_b, base_scale,
        wconv_w + 0 * 384 * 25, wscale + 0 * 384, coeffs1, coeffs2, out);
}